// Round 1
// baseline (123.765 us; speedup 1.0000x reference)
//
#include <hip/hip_runtime.h>
#include <math.h>

// GraspCVAE loss, MI355X — round 9.
// R8 counters: mega1a VALU-issue-bound (VALUBusy 86-102%, HBM 3.5%, occ 23%
// at exactly 3 blocks/CU). This round cuts VALU instructions per pair:
//   * forced v_and_or_b32 (1-instr packkey) + v_min3_f32 (1-instr 2-cand min)
//     via inline asm in all three inner loops (obj, hand, prior).
//   * hand-side padding fix: 778 pts were padded to 4x256 slots (m=3 is 97%
//     dead but ran the full k-loop). Now 3 unguarded m-passes + 10-pt tail on
//     ONE wave, rotated per block (bid2&3) to spread SIMD load.
// Dataflow unchanged from R4/R8: mega1 (768 blocks) -> mega2 (482 blocks).

#define NB 32
#define NH 778
#define NO 3000
#define NZ 64
#define NP 204

#define P_OBJ 4
#define OBJ_PTS 1024
#define OBJ_TILES 3                   // ceil(3000/1024)
#define JSPLIT 4
#define JCH 195                       // ceil(778/4)
#define HC 12                         // hand-side obj chunks
#define HCS 250                       // 3000/12
#define OBJ_BLKS (NB * OBJ_TILES * JSPLIT)    // 384
#define HAND_BLKS (NB * HC)                   // 384
#define T2 12                         // mega2 obj tiles (256 pts)
#define FIN_OBJ_BLKS (NB * T2)                // 384
#define FIN_TAIL_BLKS ((NB * NH + 255) / 256) // 98
#define FIN_BLKS (FIN_OBJ_BLKS + FIN_TAIL_BLKS) // 482

#define NKEY (NB * NO)                // 96000
#define NHT  (NB * NH)                // 24896

typedef unsigned int uint32;

// original order (used by PATH C)
__device__ __constant__ int c_prior[NP] = {
  697,698,699,700,712,713,714,715,737,738,739,740,741,743,744,745,746,748,749,750,
  753,754,755,756,757,758,759,760,761,762,763,764,765,766,767,768,
  46,47,48,49,164,165,166,167,194,195,223,237,238,280,281,298,301,317,320,323,
  324,325,326,327,328,329,330,331,332,333,340,341,342,343,344,345,346,347,348,349,
  350,351,352,353,354,355,
  356,357,358,359,375,376,386,387,396,397,402,403,413,429,433,434,435,436,437,438,
  439,440,441,442,443,444,452,453,454,455,456,459,460,461,462,463,464,465,466,467,
  468,469,470,471,484,485,486,496,497,506,507,513,514,524,545,546,547,548,549,550,
  551,552,553,555,563,564,565,566,567,570,572,573,574,575,576,577,578,
  580,581,582,583,600,601,602,614,615,624,625,630,631,641,663,664,665,666,667,668,
  670,672,680,681,682,683,684,686,687,688,689,690,691,692,693,694,695,
  73,96,98,99,772,774,775,777
};

// sorted ascending; per-JCH-split offsets: [0,13) [13,58) [58,131) [131,204)
__device__ __constant__ int c_prior_sorted[NP] = {
  // split 0: j in [0,195)  (13)
  46,47,48,49,73,96,98,99,164,165,166,167,194,
  // split 1: j in [195,390) (45)
  195,223,237,238,280,281,298,301,317,320,323,324,325,326,327,328,329,330,331,
  332,333,340,341,342,343,344,345,346,347,348,349,350,351,352,353,354,355,356,
  357,358,359,375,376,386,387,
  // split 2: j in [390,585) (73)
  396,397,402,403,413,429,433,434,435,436,437,438,439,440,441,442,443,444,452,
  453,454,455,456,459,460,461,462,463,464,465,466,467,468,469,470,471,484,485,
  486,496,497,506,507,513,514,524,545,546,547,548,549,550,551,552,553,555,563,
  564,565,566,567,570,572,573,574,575,576,577,578,580,581,582,583,
  // split 3: j in [585,778) (73)
  600,601,602,614,615,624,625,630,631,641,663,664,665,666,667,668,670,672,680,
  681,682,683,684,686,687,688,689,690,691,692,693,694,695,697,698,699,700,712,
  713,714,715,737,738,739,740,741,743,744,745,746,748,749,750,753,754,755,756,
  757,758,759,760,761,762,763,764,765,766,767,768,772,774,775,777
};
__device__ __constant__ int c_psplit[JSPLIT + 1] = {0, 13, 58, 131, 204};

__device__ inline float wave_sum(float v) {
  v += __shfl_down(v, 32);
  v += __shfl_down(v, 16);
  v += __shfl_down(v, 8);
  v += __shfl_down(v, 4);
  v += __shfl_down(v, 2);
  v += __shfl_down(v, 1);
  return v;
}

// forced 3-operand VALU ops (compiler doesn't reliably fuse these)
__device__ __forceinline__ float f_min3(float a, float b, float c) {
  float r;
  asm("v_min3_f32 %0, %1, %2, %3" : "=v"(r) : "v"(a), "v"(b), "v"(c));
  return r;
}
// (bits(t) & mask) | j  in one instruction; mask kept in SGPR (VOP3: 1 sgpr max)
__device__ __forceinline__ float f_packao(float t, int j, uint32 mask) {
  float r;
  asm("v_and_or_b32 %0, %1, %2, %3" : "=v"(r) : "v"(t), "s"(mask), "v"(j));
  return r;
}

// ======================= dispatch 1: mega1 =======================
// accs: 0 penetr, 1 npts, 2 contact, 3 consist, 4 loss_o, 5 loss_h,
//       6 recon_sq, 7 kld, 8 counter(int)
__global__ __launch_bounds__(256) void mega1a(
    const float* __restrict__ recon, const float* __restrict__ gt,
    const float* __restrict__ obj,
    float* __restrict__ keyR, float* __restrict__ keyG,
    float* __restrict__ priorK,
    float* __restrict__ minHR, float* __restrict__ minHG,
    float* __restrict__ accs)
{
  const int bid = blockIdx.x;
  const int tid = threadIdx.x;
  const uint32 KMASK = 0xFFFFFC00u;

  if (bid == 0 && tid < 16) accs[tid] = 0.0f;  // consumed after kernel boundary

  if (bid < OBJ_BLKS) {
    // ---- obj -> hand NN, j-split 4, + in-pass partial prior-NN ----
    __shared__ float4 shA[JCH];   // recon split
    __shared__ float4 shB[JCH];   // gt split
    const int b     = bid / (OBJ_TILES * JSPLIT);
    const int rem   = bid % (OBJ_TILES * JSPLIT);
    const int tile  = rem / JSPLIT;
    const int split = rem % JSPLIT;
    const int jbase = split * JCH;
    const int jcnt  = (NH - jbase < JCH) ? (NH - jbase) : JCH;

    for (int i = tid; i < jcnt; i += 256) {
      const float* p = recon + ((size_t)b * NH + jbase + i) * 3;
      float x = p[0], y = p[1], z = p[2];
      shA[i] = make_float4(x, y, z, x*x + y*y + z*z);
      const float* q = gt + ((size_t)b * NH + jbase + i) * 3;
      float gx = q[0], gy = q[1], gz = q[2];
      shB[i] = make_float4(gx, gy, gz, gx*gx + gy*gy + gz*gz);
    }
    __syncthreads();

    float nx[P_OBJ], ny[P_OBJ], nz[P_OBJ];
    int ob[P_OBJ]; bool val[P_OBJ];
    #pragma unroll
    for (int m = 0; m < P_OBJ; ++m) {
      int o = tile * OBJ_PTS + m * 256 + tid;
      ob[m] = o; val[m] = (o < NO);
      float x = 0.f, y = 0.f, z = 0.f;
      if (val[m]) {
        const float* op = obj + ((size_t)b * NO + o) * 3;
        x = op[0]; y = op[1]; z = op[2];
      }
      nx[m] = -2.f * x; ny[m] = -2.f * y; nz[m] = -2.f * z;
    }

    float bR[P_OBJ], bG[P_OBJ];
    #pragma unroll
    for (int m = 0; m < P_OBJ; ++m) { bR[m] = 3.4e38f; bG[m] = 3.4e38f; }

    int i = 0;
    for (; i + 1 < jcnt; i += 2) {
      const int j0 = jbase + i, j1 = jbase + i + 1;
      float4 h0 = shA[i], h1 = shA[i + 1];
      float4 g0 = shB[i], g1 = shB[i + 1];
      #pragma unroll
      for (int m = 0; m < P_OBJ; ++m) {
        float t0 = fmaf(nx[m], h0.x, h0.w); t0 = fmaf(ny[m], h0.y, t0); t0 = fmaf(nz[m], h0.z, t0);
        float t1 = fmaf(nx[m], h1.x, h1.w); t1 = fmaf(ny[m], h1.y, t1); t1 = fmaf(nz[m], h1.z, t1);
        bR[m] = f_min3(bR[m], f_packao(t0, j0, KMASK), f_packao(t1, j1, KMASK));
      }
      #pragma unroll
      for (int m = 0; m < P_OBJ; ++m) {
        float u0 = fmaf(nx[m], g0.x, g0.w); u0 = fmaf(ny[m], g0.y, u0); u0 = fmaf(nz[m], g0.z, u0);
        float u1 = fmaf(nx[m], g1.x, g1.w); u1 = fmaf(ny[m], g1.y, u1); u1 = fmaf(nz[m], g1.z, u1);
        bG[m] = f_min3(bG[m], f_packao(u0, j0, KMASK), f_packao(u1, j1, KMASK));
      }
    }
    if (i < jcnt) {
      const int j0 = jbase + i;
      float4 h0 = shA[i];
      float4 g0 = shB[i];
      #pragma unroll
      for (int m = 0; m < P_OBJ; ++m) {
        float t0 = fmaf(nx[m], h0.x, h0.w); t0 = fmaf(ny[m], h0.y, t0); t0 = fmaf(nz[m], h0.z, t0);
        bR[m] = fminf(bR[m], f_packao(t0, j0, KMASK));
        float u0 = fmaf(nx[m], g0.x, g0.w); u0 = fmaf(ny[m], g0.y, u0); u0 = fmaf(nz[m], g0.z, u0);
        bG[m] = fminf(bG[m], f_packao(u0, j0, KMASK));
      }
    }

    // partial prior-NN over this split's prior members (recon candidates in shA)
    float bP[P_OBJ];
    #pragma unroll
    for (int m = 0; m < P_OBJ; ++m) bP[m] = 3.4e38f;
    const int pk0 = c_psplit[split], pk1 = c_psplit[split + 1];
    int k = pk0;
    for (; k + 1 < pk1; k += 2) {
      float4 ha = shA[c_prior_sorted[k] - jbase];
      float4 hb = shA[c_prior_sorted[k + 1] - jbase];
      #pragma unroll
      for (int m = 0; m < P_OBJ; ++m) {
        float t = fmaf(nx[m], ha.x, ha.w); t = fmaf(ny[m], ha.y, t); t = fmaf(nz[m], ha.z, t);
        float u = fmaf(nx[m], hb.x, hb.w); u = fmaf(ny[m], hb.y, u); u = fmaf(nz[m], hb.z, u);
        bP[m] = f_min3(bP[m], t, u);
      }
    }
    if (k < pk1) {
      float4 ha = shA[c_prior_sorted[k] - jbase];
      #pragma unroll
      for (int m = 0; m < P_OBJ; ++m) {
        float t = fmaf(nx[m], ha.x, ha.w); t = fmaf(ny[m], ha.y, t); t = fmaf(nz[m], ha.z, t);
        bP[m] = fminf(bP[m], t);
      }
    }

    #pragma unroll
    for (int m = 0; m < P_OBJ; ++m) {
      if (!val[m]) continue;
      const size_t idx = (size_t)split * NKEY + (size_t)b * NO + ob[m];
      keyR[idx] = bR[m];
      keyG[idx] = bG[m];
      priorK[idx] = bP[m];
    }
  } else {
    // ---- hand -> obj NN, 12 chunks; 3 full m-passes + rotating-wave tail ----
    __shared__ float4 sO[HCS];
    const int bid2 = bid - OBJ_BLKS;
    const int oc = bid2 % HC;
    const int b  = bid2 / HC;

    const float* Ob = obj + ((size_t)b * NO + oc * HCS) * 3;
    for (int i2 = tid; i2 < HCS; i2 += 256) {
      float x = Ob[3*i2], y = Ob[3*i2+1], z = Ob[3*i2+2];
      sO[i2] = make_float4(x, y, z, x*x + y*y + z*z);
    }
    __syncthreads();

    float nrx[3], nry[3], nrz[3];
    float ngx[3], ngy[3], ngz[3];
    #pragma unroll
    for (int m = 0; m < 3; ++m) {
      const int j = m * 256 + tid;                 // 0..767, always valid
      const float* rp = recon + ((size_t)b * NH + j) * 3;
      const float* gp = gt    + ((size_t)b * NH + j) * 3;
      nrx[m] = -2.f*rp[0]; nry[m] = -2.f*rp[1]; nrz[m] = -2.f*rp[2];
      ngx[m] = -2.f*gp[0]; ngy[m] = -2.f*gp[1]; ngz[m] = -2.f*gp[2];
    }

    float mR[3], mG[3];
    #pragma unroll
    for (int m = 0; m < 3; ++m) { mR[m] = 3.4e38f; mG[m] = 3.4e38f; }

    for (int k2 = 0; k2 < HCS; k2 += 2) {
      float4 o0 = sO[k2], o1 = sO[k2 + 1];
      #pragma unroll
      for (int m = 0; m < 3; ++m) {
        float t0 = fmaf(nrx[m], o0.x, o0.w); t0 = fmaf(nry[m], o0.y, t0); t0 = fmaf(nrz[m], o0.z, t0);
        float t1 = fmaf(nrx[m], o1.x, o1.w); t1 = fmaf(nry[m], o1.y, t1); t1 = fmaf(nrz[m], o1.z, t1);
        mR[m] = f_min3(mR[m], t0, t1);
        float u0 = fmaf(ngx[m], o0.x, o0.w); u0 = fmaf(ngy[m], o0.y, u0); u0 = fmaf(ngz[m], o0.z, u0);
        float u1 = fmaf(ngx[m], o1.x, o1.w); u1 = fmaf(ngy[m], o1.y, u1); u1 = fmaf(ngz[m], o1.z, u1);
        mG[m] = f_min3(mG[m], u0, u1);
      }
    }

    #pragma unroll
    for (int m = 0; m < 3; ++m) {
      const int j = m * 256 + tid;
      const size_t idx = (size_t)oc * NHT + (size_t)b * NH + j;
      minHR[idx] = mR[m];
      minHG[idx] = mG[m];
    }

    // tail: hand points 768..777 on one wave, rotated per block to balance SIMDs
    const int tw = bid2 & 3;
    if ((tid >> 6) == tw) {
      const int j3 = 768 + (tid & 63);
      const bool v3 = (j3 < NH);                   // lanes 0..9
      float rx=0.f,ry=0.f,rz=0.f,gx=0.f,gy=0.f,gz=0.f;
      if (v3) {
        const float* rp = recon + ((size_t)b * NH + j3) * 3;
        const float* gp = gt    + ((size_t)b * NH + j3) * 3;
        rx=rp[0];ry=rp[1];rz=rp[2]; gx=gp[0];gy=gp[1];gz=gp[2];
      }
      const float n3rx=-2.f*rx, n3ry=-2.f*ry, n3rz=-2.f*rz;
      const float n3gx=-2.f*gx, n3gy=-2.f*gy, n3gz=-2.f*gz;
      float m3R = 3.4e38f, m3G = 3.4e38f;
      for (int k2 = 0; k2 < HCS; k2 += 2) {
        float4 o0 = sO[k2], o1 = sO[k2 + 1];
        float t0 = fmaf(n3rx, o0.x, o0.w); t0 = fmaf(n3ry, o0.y, t0); t0 = fmaf(n3rz, o0.z, t0);
        float t1 = fmaf(n3rx, o1.x, o1.w); t1 = fmaf(n3ry, o1.y, t1); t1 = fmaf(n3rz, o1.z, t1);
        m3R = f_min3(m3R, t0, t1);
        float u0 = fmaf(n3gx, o0.x, o0.w); u0 = fmaf(n3gy, o0.y, u0); u0 = fmaf(n3gz, o0.z, u0);
        float u1 = fmaf(n3gx, o1.x, o1.w); u1 = fmaf(n3gy, o1.y, u1); u1 = fmaf(n3gz, o1.z, u1);
        m3G = f_min3(m3G, u0, u1);
      }
      if (v3) {
        const size_t idx = (size_t)oc * NHT + (size_t)b * NH + j3;
        minHR[idx] = m3R;
        minHG[idx] = m3G;
      }
    }
  }
}

// ======================= dispatch 2: mega2 =======================
__global__ __launch_bounds__(256) void mega2a(
    const float* __restrict__ recon, const float* __restrict__ gt,
    const float* __restrict__ rnorm, const float* __restrict__ gnorm,
    const float* __restrict__ obj,
    const float* __restrict__ mean, const float* __restrict__ logv,
    const float* __restrict__ vw,
    const float* __restrict__ keyR, const float* __restrict__ keyG,
    const float* __restrict__ priorK,
    const float* __restrict__ minHR, const float* __restrict__ minHG,
    float* __restrict__ accs, float* __restrict__ out)
{
  __shared__ float red[4][5];
  const int bid = blockIdx.x;
  const int tid = threadIdx.x;
  const int lane = tid & 63, wv = tid >> 6;

  if (bid < FIN_OBJ_BLKS) {
    // ---- obj finalize: 12 slice loads + 2 gathers + epilogue (no staging) ----
    const int b = bid / T2;
    const int tile = bid % T2;
    const int o = tile * 256 + tid;
    float penetr = 0.f, nptsv = 0.f, contactv = 0.f, consistv = 0.f, lossov = 0.f;
    if (o < NO) {
      const float* op = obj + ((size_t)b * NO + o) * 3;
      const float ox = op[0], oy = op[1], oz = op[2];
      const float o2 = ox*ox + oy*oy + oz*oz;
      const size_t base = (size_t)b * NO + o;

      float kR = 3.4e38f, kG = 3.4e38f, bP = 3.4e38f;
      #pragma unroll
      for (int s = 0; s < JSPLIT; ++s) {
        kR = fminf(kR, keyR[(size_t)s * NKEY + base]);
        kG = fminf(kG, keyG[(size_t)s * NKEY + base]);
        bP = fminf(bP, priorK[(size_t)s * NKEY + base]);
      }
      uint32 kRb = __float_as_uint(kR), kGb = __float_as_uint(kG);
      int idxR = (int)(kRb & 0x3FFu), idxG = (int)(kGb & 0x3FFu);
      float d2R = fmaxf(__uint_as_float(kRb & 0xFFFFFC00u) + o2, 0.f);
      float d2G = fmaxf(__uint_as_float(kGb & 0xFFFFFC00u) + o2, 0.f);
      float d2P = fmaxf(bP + o2, 0.f);

      const float* hR = recon + ((size_t)b * NH + idxR) * 3;
      const float* nR = rnorm + ((size_t)b * NH + idxR) * 3;
      float dotR = (ox - hR[0]) * nR[0] + (oy - hR[1]) * nR[1] + (oz - hR[2]) * nR[2];
      const float* hG = gt + ((size_t)b * NH + idxG) * 3;
      const float* nG = gnorm + ((size_t)b * NH + idxG) * 3;
      float dotG = (ox - hG[0]) * nG[0] + (oy - hG[1]) * nG[1] + (oz - hG[2]) * nG[2];

      float sgnR = (dotR > 0.f) ? 1.f : ((dotR < 0.f) ? -1.f : 0.f);
      float sgnG = (dotG > 0.f) ? 1.f : ((dotG < 0.f) ? -1.f : 0.f);
      float sR_ = sqrtf(d2R), sG_ = sqrtf(d2G);
      float o2h = sR_ * sgnR, o2hg = sG_ * sgnG;

      bool interior = dotR < 0.f;
      bool cmap = sG_ < 0.005f;
      bool rcmap = sR_ < 0.005f;

      penetr   = interior ? d2R : 0.f;
      nptsv    = cmap ? 1.f : 0.f;
      contactv = cmap ? d2P : 0.f;
      consistv = (cmap && rcmap) ? 1.f : 0.f;
      float w = (o2h < 0.f) ? 1.5f
              : (((o2hg < 0.01f) && (o2hg > -0.005f)) ? 1.f : 0.1f);
      lossov = fabsf(o2h - o2hg) * w;
    }

    float vals[5] = {penetr, nptsv, contactv, consistv, lossov};
    #pragma unroll
    for (int q = 0; q < 5; ++q) {
      float s = wave_sum(vals[q]);
      if (lane == 0) red[wv][q] = s;
    }
    __syncthreads();
    if (tid < 5) {
      float s = red[0][tid] + red[1][tid] + red[2][tid] + red[3][tid];
      atomicAdd(&accs[tid], s);
    }
  } else {
    // ---- tail: reduce hand-chunk mins, loss_h, recon_loss, KLD ----
    const int t = (bid - FIN_OBJ_BLKS) * 256 + tid;
    float lossh = 0.f, rsum = 0.f, ksum = 0.f;
    if (t < NB * NH) {
      const float* rp = recon + (size_t)t * 3;
      const float* gp = gt + (size_t)t * 3;
      float rx = rp[0], ry = rp[1], rz = rp[2];
      float gx = gp[0], gy = gp[1], gz = gp[2];
      float d0 = rx - gx, d1 = ry - gy, d2 = rz - gz;
      rsum = d0*d0 + d1*d1 + d2*d2;

      float tR[HC], tG[HC];
      #pragma unroll
      for (int c = 0; c < HC; ++c) {
        tR[c] = minHR[(size_t)c * NHT + t];
        tG[c] = minHG[(size_t)c * NHT + t];
      }
      float mRt = tR[0], mGt = tG[0];
      #pragma unroll
      for (int c = 1; c < HC; ++c) {
        mRt = fminf(mRt, tR[c]);
        mGt = fminf(mGt, tG[c]);
      }
      float r2 = rx*rx + ry*ry + rz*rz;
      float g2 = gx*gx + gy*gy + gz*gz;
      float d2Rh = fmaxf(mRt + r2, 0.f);
      float d2Gh = fmaxf(mGt + g2, 0.f);
      int j = t % NH;
      lossh = fabsf(sqrtf(d2Rh) - sqrtf(d2Gh)) * powf(vw[j], 0.4f);
    }
    if (t < NB * NZ) {
      float m = mean[t], lv = logv[t];
      ksum = 1.f + lv - m * m - expf(lv);
    }
    float vals[3] = {lossh, rsum, ksum};
    #pragma unroll
    for (int q = 0; q < 3; ++q) {
      float s = wave_sum(vals[q]);
      if (lane == 0) red[wv][q] = s;
    }
    __syncthreads();
    if (tid < 3) {
      float s = red[0][tid] + red[1][tid] + red[2][tid] + red[3][tid];
      atomicAdd(&accs[5 + tid], s);
    }
  }

  // ---- fused final: last block combines ----
  __syncthreads();
  if (tid == 0) {
    __threadfence();
    int* cnt = (int*)(accs + 8);
    int old = atomicAdd(cnt, 1);
    if (old == FIN_BLKS - 1) {
      float a[8];
      #pragma unroll
      for (int q = 0; q < 8; ++q) a[q] = atomicAdd(&accs[q], 0.0f);
      const float recon_loss = a[6] / (float)NB;
      const float kld = -0.5f * a[7] / (float)NB * 10.f;
      const float penetr = 100.f * a[0] / (float)NB;
      const float npts = a[1];
      const float contact = (npts > 0.f) ? (3000.f * a[2] / ((float)NB * npts)) : 0.f;
      const float consistency = -5.f * a[3] / (npts + 0.0001f);
      const float lossh = 35.f * (1.f - 0.005f) * (a[5] / (float)(NB * NH));
      const float losso = 30.f * (1.f - 0.005f) * (a[4] / (float)(NB * NO));
      out[0] = recon_loss + 0.1f * kld + 1000.f * penetr + 10.f * contact
             + 10.f * consistency + lossh + losso;
    }
  }
}

// =========================== PATH C (tiny ws fallback) ===========================
__global__ __launch_bounds__(256) void obj_mono(
    const float* __restrict__ recon, const float* __restrict__ gt,
    const float* __restrict__ rnorm, const float* __restrict__ gnorm,
    const float* __restrict__ obj, float* __restrict__ accs)
{
  __shared__ float4 sR[NH];
  __shared__ float4 sG[NH];
  __shared__ float red[4][5];
  const int b = blockIdx.x / 12;
  const int tile = blockIdx.x % 12;
  const int tid = threadIdx.x;
  for (int i = tid; i < NH; i += 256) {
    const float* p = recon + ((size_t)b * NH + i) * 3;
    float x = p[0], y = p[1], z = p[2];
    sR[i] = make_float4(x, y, z, x*x + y*y + z*z);
    const float* q = gt + ((size_t)b * NH + i) * 3;
    float gx = q[0], gy = q[1], gz = q[2];
    sG[i] = make_float4(gx, gy, gz, gx*gx + gy*gy + gz*gz);
  }
  __syncthreads();
  const int o = tile * 256 + tid;
  float penetr = 0.f, nptsv = 0.f, contactv = 0.f, consistv = 0.f, lossov = 0.f;
  if (o < NO) {
    const float* op = obj + ((size_t)b * NO + o) * 3;
    const float ox = op[0], oy = op[1], oz = op[2];
    const float nx = -2.f*ox, ny = -2.f*oy, nz = -2.f*oz;
    const float o2 = ox*ox + oy*oy + oz*oz;
    float bR = 3.4e38f, bG = 3.4e38f; int iR = 0, iG = 0;
    for (int i = 0; i < NH; ++i) {
      float4 h = sR[i];
      float t = fmaf(nx, h.x, h.w); t = fmaf(ny, h.y, t); t = fmaf(nz, h.z, t);
      if (t < bR) { bR = t; iR = i; }
      float4 g = sG[i];
      float u = fmaf(nx, g.x, g.w); u = fmaf(ny, g.y, u); u = fmaf(nz, g.z, u);
      if (u < bG) { bG = u; iG = i; }
    }
    float bP = 3.4e38f;
    for (int k = 0; k < NP; ++k) {
      float4 h = sR[c_prior[k]];
      float t = fmaf(nx, h.x, h.w); t = fmaf(ny, h.y, t); t = fmaf(nz, h.z, t);
      bP = fminf(bP, t);
    }
    float d2R = fmaxf(bR + o2, 0.f);
    float d2G = fmaxf(bG + o2, 0.f);
    float d2P = fmaxf(bP + o2, 0.f);
    float4 hR = sR[iR];
    const float* nR = rnorm + ((size_t)b * NH + iR) * 3;
    float dotR = (ox-hR.x)*nR[0] + (oy-hR.y)*nR[1] + (oz-hR.z)*nR[2];
    float4 hG = sG[iG];
    const float* nG = gnorm + ((size_t)b * NH + iG) * 3;
    float dotG = (ox-hG.x)*nG[0] + (oy-hG.y)*nG[1] + (oz-hG.z)*nG[2];
    float sgnR = (dotR > 0.f) ? 1.f : ((dotR < 0.f) ? -1.f : 0.f);
    float sgnG = (dotG > 0.f) ? 1.f : ((dotG < 0.f) ? -1.f : 0.f);
    float sR_ = sqrtf(d2R), sG_ = sqrtf(d2G);
    float o2h = sR_*sgnR, o2hg = sG_*sgnG;
    bool interior = dotR < 0.f;
    bool cmap = sG_ < 0.005f, rcmap = sR_ < 0.005f;
    penetr = interior ? d2R : 0.f;
    nptsv = cmap ? 1.f : 0.f;
    contactv = cmap ? d2P : 0.f;
    consistv = (cmap && rcmap) ? 1.f : 0.f;
    float w = (o2h < 0.f) ? 1.5f : (((o2hg < 0.01f) && (o2hg > -0.005f)) ? 1.f : 0.1f);
    lossov = fabsf(o2h - o2hg) * w;
  }
  float vals[5] = {penetr, nptsv, contactv, consistv, lossov};
  const int lane = tid & 63, wv = tid >> 6;
  for (int q = 0; q < 5; ++q) {
    float s = wave_sum(vals[q]);
    if (lane == 0) red[wv][q] = s;
  }
  __syncthreads();
  if (tid < 5) {
    float s = red[0][tid] + red[1][tid] + red[2][tid] + red[3][tid];
    atomicAdd(&accs[tid], s);
  }
}

__global__ __launch_bounds__(256) void hand_full(
    const float* __restrict__ recon, const float* __restrict__ gt,
    const float* __restrict__ obj, const float* __restrict__ vw,
    float* __restrict__ accs)
{
  __shared__ float4 sO[500];
  __shared__ float red[4];
  const int b = blockIdx.x >> 2;
  const int j = ((blockIdx.x & 3) << 8) + threadIdx.x;
  const bool valid = j < NH;
  float rx=0,ry=0,rz=0,gx=0,gy=0,gz=0;
  if (valid) {
    const float* rp = recon + ((size_t)b * NH + j) * 3;
    const float* gp = gt + ((size_t)b * NH + j) * 3;
    rx=rp[0];ry=rp[1];rz=rp[2]; gx=gp[0];gy=gp[1];gz=gp[2];
  }
  const float nrx=-2.f*rx, nry=-2.f*ry, nrz=-2.f*rz;
  const float ngx=-2.f*gx, ngy=-2.f*gy, ngz=-2.f*gz;
  const float r2 = rx*rx+ry*ry+rz*rz, g2 = gx*gx+gy*gy+gz*gz;
  float mR = 3.4e38f, mG = 3.4e38f;
  for (int oc = 0; oc < 6; ++oc) {
    __syncthreads();
    const float* Ob = obj + ((size_t)b * NO + oc * 500) * 3;
    for (int i = threadIdx.x; i < 500; i += 256) {
      float x = Ob[3*i], y = Ob[3*i+1], z = Ob[3*i+2];
      sO[i] = make_float4(x, y, z, x*x + y*y + z*z);
    }
    __syncthreads();
    if (valid) {
      for (int k = 0; k < 500; ++k) {
        float4 o4 = sO[k];
        float t = fmaf(nrx,o4.x,o4.w); t = fmaf(nry,o4.y,t); t = fmaf(nrz,o4.z,t);
        mR = fminf(mR, t);
        float u = fmaf(ngx,o4.x,o4.w); u = fmaf(ngy,o4.y,u); u = fmaf(ngz,o4.z,u);
        mG = fminf(mG, u);
      }
    }
  }
  float lossh = valid ? fabsf(sqrtf(fmaxf(mR+r2,0.f)) - sqrtf(fmaxf(mG+g2,0.f))) * powf(vw[j], 0.4f) : 0.f;
  const int lane = threadIdx.x & 63, wv = threadIdx.x >> 6;
  float s = wave_sum(lossh);
  if (lane == 0) red[wv] = s;
  __syncthreads();
  if (threadIdx.x == 0) atomicAdd(&accs[5], red[0]+red[1]+red[2]+red[3]);
}

__global__ __launch_bounds__(256) void tail_nomins(
    const float* __restrict__ recon, const float* __restrict__ gt,
    const float* __restrict__ mean, const float* __restrict__ logv,
    float* __restrict__ accs)
{
  __shared__ float red[4][2];
  const int t = blockIdx.x * 256 + threadIdx.x;
  float rsum = 0.f, ksum = 0.f;
  if (t < NB * NH) {
    const float* rp = recon + (size_t)t * 3;
    const float* gp = gt + (size_t)t * 3;
    float d0 = rp[0]-gp[0], d1 = rp[1]-gp[1], d2 = rp[2]-gp[2];
    rsum = d0*d0 + d1*d1 + d2*d2;
  }
  if (t < NB * NZ) {
    float m = mean[t], lv = logv[t];
    ksum = 1.f + lv - m*m - expf(lv);
  }
  float vals[2] = {rsum, ksum};
  const int lane = threadIdx.x & 63, wv = threadIdx.x >> 6;
  for (int q = 0; q < 2; ++q) {
    float s = wave_sum(vals[q]);
    if (lane == 0) red[wv][q] = s;
  }
  __syncthreads();
  if (threadIdx.x < 2) {
    float s = red[0][threadIdx.x] + red[1][threadIdx.x] + red[2][threadIdx.x] + red[3][threadIdx.x];
    atomicAdd(&accs[6 + threadIdx.x], s);
  }
}

__global__ void init_small(float* accs) {
  int t = threadIdx.x;
  if (t < 8) accs[t] = 0.0f;
}

__global__ void final_fb(const float* __restrict__ a, float* __restrict__ out) {
  const float recon_loss = a[6] / (float)NB;
  const float kld = -0.5f * a[7] / (float)NB * 10.f;
  const float penetr = 100.f * a[0] / (float)NB;
  const float npts = a[1];
  const float contact = (npts > 0.f) ? (3000.f * a[2] / ((float)NB * npts)) : 0.f;
  const float consistency = -5.f * a[3] / (npts + 0.0001f);
  const float lossh = 35.f * (1.f - 0.005f) * (a[5] / (float)NB / (float)NH);
  const float losso = 30.f * (1.f - 0.005f) * (a[4] / (float)(NB * NO));
  out[0] = recon_loss + 0.1f*kld + 1000.f*penetr + 10.f*contact + 10.f*consistency + lossh + losso;
}

extern "C" void kernel_launch(void* const* d_in, const int* in_sizes, int n_in,
                              void* d_out, int out_size, void* d_ws, size_t ws_size,
                              hipStream_t stream) {
  const float* recon = (const float*)d_in[0];
  const float* gt    = (const float*)d_in[1];
  const float* rnorm = (const float*)d_in[2];
  const float* gnorm = (const float*)d_in[3];
  const float* obj   = (const float*)d_in[4];
  const float* mean  = (const float*)d_in[5];
  const float* logv  = (const float*)d_in[6];
  const float* vw    = (const float*)d_in[7];
  float* out = (float*)d_out;

  // ws: accs[16] @0 | slices @256: keyR[4N] keyG[4N] priorK[4N] minHR[12H] minHG[12H]
  float* accs   = (float*)d_ws;
  float* keyR   = (float*)((char*)d_ws + 256);
  float* keyG   = keyR + (size_t)JSPLIT * NKEY;
  float* priorK = keyG + (size_t)JSPLIT * NKEY;
  float* minHR  = priorK + (size_t)JSPLIT * NKEY;
  float* minHG  = minHR + (size_t)HC * NHT;
  const size_t neededA = 256 + (3ull * JSPLIT * NKEY + 2ull * HC * NHT) * sizeof(float);

  if (ws_size >= neededA) {
    mega1a<<<OBJ_BLKS + HAND_BLKS, 256, 0, stream>>>(
        recon, gt, obj, keyR, keyG, priorK, minHR, minHG, accs);
    mega2a<<<FIN_BLKS, 256, 0, stream>>>(
        recon, gt, rnorm, gnorm, obj, mean, logv, vw,
        keyR, keyG, priorK, minHR, minHG, accs, out);
  } else {
    init_small<<<1, 64, 0, stream>>>(accs);
    obj_mono<<<NB * 12, 256, 0, stream>>>(recon, gt, rnorm, gnorm, obj, accs);
    hand_full<<<NB * 4, 256, 0, stream>>>(recon, gt, obj, vw, accs);
    tail_nomins<<<(NB * NH + 255) / 256, 256, 0, stream>>>(recon, gt, mean, logv, accs);
    final_fb<<<1, 1, 0, stream>>>(accs, out);
  }
}

// Round 2
// 123.585 us; speedup vs baseline: 1.0015x; 1.0015x over previous
//
#include <hip/hip_runtime.h>
#include <math.h>

// GraspCVAE loss, MI355X — round 10.
// R9 post-mortem: cutting VALU instrs (min3/and_or fusion) dropped VALUBusy
// 92->77% at UNCHANGED 42us -> mega1a is NOT VALU-issue-bound. Arithmetic:
// ~23M wave-instrs = ~19us pure issue = ~45% per-SIMD utilization. With only
// 3 blocks/CU (grid 768) and loop shape [4 broadcast ds_reads -> waitcnt ->
// 72 VALU], waves convoy on LDS latency (28 VGPR = compiler didn't pipeline).
// R10 attacks latency hiding two ways:
//   * tiered fine split (JSPLIT 8, HC 24 -> 1536 blocks = 6 blocks/CU) when
//     workspace >= 14MB; falls back to the old 4/12 split (7MB), then PATH C.
//   * register double-buffer prefetch in all inner loops; obj-side interleaved
//     [load G(i) | compute R | load A(i+2) | compute G] so each LDS wait is
//     covered by ~36 VALU.
// Dispatches: mega1 (block 0 zeroes accs) -> mega2 (482 blocks, last block
// combines into out[0] via counter in accs[8]).

#define NB 32
#define NH 778
#define NO 3000
#define NZ 64
#define NP 204

#define P_OBJ 4
#define OBJ_PTS 1024
#define OBJ_TILES 3                   // ceil(3000/1024)

#define T2 12                         // mega2 obj tiles (256 pts)
#define FIN_OBJ_BLKS (NB * T2)                // 384
#define FIN_TAIL_BLKS ((NB * NH + 255) / 256) // 98
#define FIN_BLKS (FIN_OBJ_BLKS + FIN_TAIL_BLKS) // 482

#define NKEY (NB * NO)                // 96000
#define NHT  (NB * NH)                // 24896

typedef unsigned int uint32;

// original order (used by PATH C)
__device__ __constant__ int c_prior[NP] = {
  697,698,699,700,712,713,714,715,737,738,739,740,741,743,744,745,746,748,749,750,
  753,754,755,756,757,758,759,760,761,762,763,764,765,766,767,768,
  46,47,48,49,164,165,166,167,194,195,223,237,238,280,281,298,301,317,320,323,
  324,325,326,327,328,329,330,331,332,333,340,341,342,343,344,345,346,347,348,349,
  350,351,352,353,354,355,
  356,357,358,359,375,376,386,387,396,397,402,403,413,429,433,434,435,436,437,438,
  439,440,441,442,443,444,452,453,454,455,456,459,460,461,462,463,464,465,466,467,
  468,469,470,471,484,485,486,496,497,506,507,513,514,524,545,546,547,548,549,550,
  551,552,553,555,563,564,565,566,567,570,572,573,574,575,576,577,578,
  580,581,582,583,600,601,602,614,615,624,625,630,631,641,663,664,665,666,667,668,
  670,672,680,681,682,683,684,686,687,688,689,690,691,692,693,694,695,
  73,96,98,99,772,774,775,777
};

// globally ascending sorted prior list (usable for ANY contiguous j-split)
__device__ __constant__ int c_prior_sorted[NP] = {
  46,47,48,49,73,96,98,99,164,165,166,167,194,
  195,223,237,238,280,281,298,301,317,320,323,324,325,326,327,328,329,330,331,
  332,333,340,341,342,343,344,345,346,347,348,349,350,351,352,353,354,355,356,
  357,358,359,375,376,386,387,
  396,397,402,403,413,429,433,434,435,436,437,438,439,440,441,442,443,444,452,
  453,454,455,456,459,460,461,462,463,464,465,466,467,468,469,470,471,484,485,
  486,496,497,506,507,513,514,524,545,546,547,548,549,550,551,552,553,555,563,
  564,565,566,567,570,572,573,574,575,576,577,578,580,581,582,583,
  600,601,602,614,615,624,625,630,631,641,663,664,665,666,667,668,670,672,680,
  681,682,683,684,686,687,688,689,690,691,692,693,694,695,697,698,699,700,712,
  713,714,715,737,738,739,740,741,743,744,745,746,748,749,750,753,754,755,756,
  757,758,759,760,761,762,763,764,765,766,767,768,772,774,775,777
};
// split tables: position ranges in c_prior_sorted for j in [s*JC, (s+1)*JC)
__device__ __constant__ int c_psplit4[5] = {0, 13, 58, 131, 204};          // JC=195
__device__ __constant__ int c_psplit8[9] = {0, 6, 14, 19, 58, 97, 131, 154, 204}; // JC=98

__device__ inline float wave_sum(float v) {
  v += __shfl_down(v, 32);
  v += __shfl_down(v, 16);
  v += __shfl_down(v, 8);
  v += __shfl_down(v, 4);
  v += __shfl_down(v, 2);
  v += __shfl_down(v, 1);
  return v;
}

// forced 3-operand VALU ops (R9: verified correct, keeps instr count down)
__device__ __forceinline__ float f_min3(float a, float b, float c) {
  float r;
  asm("v_min3_f32 %0, %1, %2, %3" : "=v"(r) : "v"(a), "v"(b), "v"(c));
  return r;
}
__device__ __forceinline__ float f_packao(float t, int j, uint32 mask) {
  float r;
  asm("v_and_or_b32 %0, %1, %2, %3" : "=v"(r) : "v"(t), "s"(mask), "v"(j));
  return r;
}

// ======================= dispatch 1: mega1 (templated on split) ==============
// accs: 0 penetr, 1 npts, 2 contact, 3 consist, 4 loss_o, 5 loss_h,
//       6 recon_sq, 7 kld, 8 counter(int)
template<int JS, int JC, int HCn, int HCSn>
__global__ __launch_bounds__(256) void mega1t(
    const float* __restrict__ recon, const float* __restrict__ gt,
    const float* __restrict__ obj,
    float* __restrict__ keyR, float* __restrict__ keyG,
    float* __restrict__ priorK,
    float* __restrict__ minHR, float* __restrict__ minHG,
    float* __restrict__ accs)
{
  const int OBJ_B = NB * OBJ_TILES * JS;
  const int bid = blockIdx.x;
  const int tid = threadIdx.x;
  const uint32 KMASK = 0xFFFFFC00u;

  if (bid == 0 && tid < 16) accs[tid] = 0.0f;  // consumed after kernel boundary

  if (bid < OBJ_B) {
    // ---- obj -> hand NN (j-split JS) + in-pass partial prior-NN ----
    __shared__ float4 shA[JC];   // recon split
    __shared__ float4 shB[JC];   // gt split
    const int b     = bid / (OBJ_TILES * JS);
    const int rem   = bid % (OBJ_TILES * JS);
    const int tile  = rem / JS;
    const int split = rem % JS;
    const int jbase = split * JC;
    const int jcnt  = (NH - jbase < JC) ? (NH - jbase) : JC;

    for (int i = tid; i < jcnt; i += 256) {
      const float* p = recon + ((size_t)b * NH + jbase + i) * 3;
      float x = p[0], y = p[1], z = p[2];
      shA[i] = make_float4(x, y, z, x*x + y*y + z*z);
      const float* q = gt + ((size_t)b * NH + jbase + i) * 3;
      float gx = q[0], gy = q[1], gz = q[2];
      shB[i] = make_float4(gx, gy, gz, gx*gx + gy*gy + gz*gz);
    }
    __syncthreads();

    float nx[P_OBJ], ny[P_OBJ], nz[P_OBJ];
    int ob[P_OBJ]; bool val[P_OBJ];
    #pragma unroll
    for (int m = 0; m < P_OBJ; ++m) {
      int o = tile * OBJ_PTS + m * 256 + tid;
      ob[m] = o; val[m] = (o < NO);
      float x = 0.f, y = 0.f, z = 0.f;
      if (val[m]) {
        const float* op = obj + ((size_t)b * NO + o) * 3;
        x = op[0]; y = op[1]; z = op[2];
      }
      nx[m] = -2.f * x; ny[m] = -2.f * y; nz[m] = -2.f * z;
    }

    float bR[P_OBJ], bG[P_OBJ];
    #pragma unroll
    for (int m = 0; m < P_OBJ; ++m) { bR[m] = 3.4e38f; bG[m] = 3.4e38f; }

#define RSTEP(hh0, hh1, jj0, jj1) \
    { _Pragma("unroll") for (int m = 0; m < P_OBJ; ++m) { \
        float t0 = fmaf(nx[m], hh0.x, hh0.w); t0 = fmaf(ny[m], hh0.y, t0); t0 = fmaf(nz[m], hh0.z, t0); \
        float t1 = fmaf(nx[m], hh1.x, hh1.w); t1 = fmaf(ny[m], hh1.y, t1); t1 = fmaf(nz[m], hh1.z, t1); \
        bR[m] = f_min3(bR[m], f_packao(t0, jj0, KMASK), f_packao(t1, jj1, KMASK)); } }
#define GSTEP(gg0, gg1, jj0, jj1) \
    { _Pragma("unroll") for (int m = 0; m < P_OBJ; ++m) { \
        float u0 = fmaf(nx[m], gg0.x, gg0.w); u0 = fmaf(ny[m], gg0.y, u0); u0 = fmaf(nz[m], gg0.z, u0); \
        float u1 = fmaf(nx[m], gg1.x, gg1.w); u1 = fmaf(ny[m], gg1.y, u1); u1 = fmaf(nz[m], gg1.z, u1); \
        bG[m] = f_min3(bG[m], f_packao(u0, jj0, KMASK), f_packao(u1, jj1, KMASK)); } }

    // interleaved prefetch: every LDS read pair is covered by a 36-VALU phase
    float4 h0 = shA[0], h1 = shA[1];
    int i = 0;
    for (; i + 3 < jcnt; i += 2) {
      float4 g0 = shB[i], g1 = shB[i + 1];     // issue G loads
      RSTEP(h0, h1, jbase + i, jbase + i + 1); // compute R (covers G latency)
      float4 hn0 = shA[i + 2], hn1 = shA[i + 3]; // issue next A loads
      GSTEP(g0, g1, jbase + i, jbase + i + 1); // compute G (covers A latency)
      h0 = hn0; h1 = hn1;
    }
    { // last preloaded pair (i, i+1 valid by loop parity)
      float4 g0 = shB[i], g1 = shB[i + 1];
      RSTEP(h0, h1, jbase + i, jbase + i + 1);
      GSTEP(g0, g1, jbase + i, jbase + i + 1);
      i += 2;
    }
    for (; i < jcnt; ++i) {      // 0-1 leftover singles
      float4 hh = shA[i], gg = shB[i];
      #pragma unroll
      for (int m = 0; m < P_OBJ; ++m) {
        float t0 = fmaf(nx[m], hh.x, hh.w); t0 = fmaf(ny[m], hh.y, t0); t0 = fmaf(nz[m], hh.z, t0);
        bR[m] = fminf(bR[m], f_packao(t0, jbase + i, KMASK));
        float u0 = fmaf(nx[m], gg.x, gg.w); u0 = fmaf(ny[m], gg.y, u0); u0 = fmaf(nz[m], gg.z, u0);
        bG[m] = fminf(bG[m], f_packao(u0, jbase + i, KMASK));
      }
    }
#undef RSTEP
#undef GSTEP

    // partial prior-NN over this split's prior members (candidates in shA)
    float bP[P_OBJ];
    #pragma unroll
    for (int m = 0; m < P_OBJ; ++m) bP[m] = 3.4e38f;
    const int* psp = (JS == 8) ? c_psplit8 : c_psplit4;
    const int pk0 = psp[split], pk1 = psp[split + 1];
    int k = pk0;
    for (; k + 1 < pk1; k += 2) {
      float4 ha = shA[c_prior_sorted[k] - jbase];
      float4 hb = shA[c_prior_sorted[k + 1] - jbase];
      #pragma unroll
      for (int m = 0; m < P_OBJ; ++m) {
        float t = fmaf(nx[m], ha.x, ha.w); t = fmaf(ny[m], ha.y, t); t = fmaf(nz[m], ha.z, t);
        float u = fmaf(nx[m], hb.x, hb.w); u = fmaf(ny[m], hb.y, u); u = fmaf(nz[m], hb.z, u);
        bP[m] = f_min3(bP[m], t, u);
      }
    }
    if (k < pk1) {
      float4 ha = shA[c_prior_sorted[k] - jbase];
      #pragma unroll
      for (int m = 0; m < P_OBJ; ++m) {
        float t = fmaf(nx[m], ha.x, ha.w); t = fmaf(ny[m], ha.y, t); t = fmaf(nz[m], ha.z, t);
        bP[m] = fminf(bP[m], t);
      }
    }

    #pragma unroll
    for (int m = 0; m < P_OBJ; ++m) {
      if (!val[m]) continue;
      const size_t idx = (size_t)split * NKEY + (size_t)b * NO + ob[m];
      keyR[idx] = bR[m];
      keyG[idx] = bG[m];
      priorK[idx] = bP[m];
    }
  } else {
    // ---- hand -> obj NN, HCn chunks; prefetched k-loop + rotating tail ----
    __shared__ float4 sO[HCSn];
    const int bid2 = bid - OBJ_B;
    const int oc = bid2 % HCn;
    const int b  = bid2 / HCn;

    const float* Ob = obj + ((size_t)b * NO + oc * HCSn) * 3;
    for (int i2 = tid; i2 < HCSn; i2 += 256) {
      float x = Ob[3*i2], y = Ob[3*i2+1], z = Ob[3*i2+2];
      sO[i2] = make_float4(x, y, z, x*x + y*y + z*z);
    }
    __syncthreads();

    float nrx[3], nry[3], nrz[3];
    float ngx[3], ngy[3], ngz[3];
    #pragma unroll
    for (int m = 0; m < 3; ++m) {
      const int j = m * 256 + tid;                 // 0..767, always valid
      const float* rp = recon + ((size_t)b * NH + j) * 3;
      const float* gp = gt    + ((size_t)b * NH + j) * 3;
      nrx[m] = -2.f*rp[0]; nry[m] = -2.f*rp[1]; nrz[m] = -2.f*rp[2];
      ngx[m] = -2.f*gp[0]; ngy[m] = -2.f*gp[1]; ngz[m] = -2.f*gp[2];
    }

    float mR[3], mG[3];
    #pragma unroll
    for (int m = 0; m < 3; ++m) { mR[m] = 3.4e38f; mG[m] = 3.4e38f; }

#define HSTEP(oo0, oo1) \
    { _Pragma("unroll") for (int m = 0; m < 3; ++m) { \
        float t0 = fmaf(nrx[m], oo0.x, oo0.w); t0 = fmaf(nry[m], oo0.y, t0); t0 = fmaf(nrz[m], oo0.z, t0); \
        float t1 = fmaf(nrx[m], oo1.x, oo1.w); t1 = fmaf(nry[m], oo1.y, t1); t1 = fmaf(nrz[m], oo1.z, t1); \
        mR[m] = f_min3(mR[m], t0, t1); \
        float u0 = fmaf(ngx[m], oo0.x, oo0.w); u0 = fmaf(ngy[m], oo0.y, u0); u0 = fmaf(ngz[m], oo0.z, u0); \
        float u1 = fmaf(ngx[m], oo1.x, oo1.w); u1 = fmaf(ngy[m], oo1.y, u1); u1 = fmaf(ngz[m], oo1.z, u1); \
        mG[m] = f_min3(mG[m], u0, u1); } }

    float4 o0 = sO[0], o1 = sO[1];
    int k2 = 0;
    for (; k2 + 3 < HCSn; k2 += 2) {
      float4 a0 = sO[k2 + 2], a1 = sO[k2 + 3];   // prefetch next pair
      HSTEP(o0, o1);
      o0 = a0; o1 = a1;
    }
    HSTEP(o0, o1);                                // last preloaded pair
    k2 += 2;
    for (; k2 < HCSn; ++k2) {                     // 0-1 leftover singles
      float4 oc4 = sO[k2];
      #pragma unroll
      for (int m = 0; m < 3; ++m) {
        float t0 = fmaf(nrx[m], oc4.x, oc4.w); t0 = fmaf(nry[m], oc4.y, t0); t0 = fmaf(nrz[m], oc4.z, t0);
        mR[m] = fminf(mR[m], t0);
        float u0 = fmaf(ngx[m], oc4.x, oc4.w); u0 = fmaf(ngy[m], oc4.y, u0); u0 = fmaf(ngz[m], oc4.z, u0);
        mG[m] = fminf(mG[m], u0);
      }
    }
#undef HSTEP

    #pragma unroll
    for (int m = 0; m < 3; ++m) {
      const int j = m * 256 + tid;
      const size_t idx = (size_t)oc * NHT + (size_t)b * NH + j;
      minHR[idx] = mR[m];
      minHG[idx] = mG[m];
    }

    // tail: hand points 768..777 on one wave, rotated per block
    const int tw = bid2 & 3;
    if ((tid >> 6) == tw) {
      const int j3 = 768 + (tid & 63);
      const bool v3 = (j3 < NH);                   // lanes 0..9
      float rx=0.f,ry=0.f,rz=0.f,gx=0.f,gy=0.f,gz=0.f;
      if (v3) {
        const float* rp = recon + ((size_t)b * NH + j3) * 3;
        const float* gp = gt    + ((size_t)b * NH + j3) * 3;
        rx=rp[0];ry=rp[1];rz=rp[2]; gx=gp[0];gy=gp[1];gz=gp[2];
      }
      const float n3rx=-2.f*rx, n3ry=-2.f*ry, n3rz=-2.f*rz;
      const float n3gx=-2.f*gx, n3gy=-2.f*gy, n3gz=-2.f*gz;
      float m3R = 3.4e38f, m3G = 3.4e38f;
      int k3 = 0;
      for (; k3 + 1 < HCSn; k3 += 2) {
        float4 q0 = sO[k3], q1 = sO[k3 + 1];
        float t0 = fmaf(n3rx, q0.x, q0.w); t0 = fmaf(n3ry, q0.y, t0); t0 = fmaf(n3rz, q0.z, t0);
        float t1 = fmaf(n3rx, q1.x, q1.w); t1 = fmaf(n3ry, q1.y, t1); t1 = fmaf(n3rz, q1.z, t1);
        m3R = f_min3(m3R, t0, t1);
        float u0 = fmaf(n3gx, q0.x, q0.w); u0 = fmaf(n3gy, q0.y, u0); u0 = fmaf(n3gz, q0.z, u0);
        float u1 = fmaf(n3gx, q1.x, q1.w); u1 = fmaf(n3gy, q1.y, u1); u1 = fmaf(n3gz, q1.z, u1);
        m3G = f_min3(m3G, u0, u1);
      }
      if (HCSn & 1) {
        float4 q0 = sO[HCSn - 1];
        float t0 = fmaf(n3rx, q0.x, q0.w); t0 = fmaf(n3ry, q0.y, t0); t0 = fmaf(n3rz, q0.z, t0);
        m3R = fminf(m3R, t0);
        float u0 = fmaf(n3gx, q0.x, q0.w); u0 = fmaf(n3gy, q0.y, u0); u0 = fmaf(n3gz, q0.z, u0);
        m3G = fminf(m3G, u0);
      }
      if (v3) {
        const size_t idx = (size_t)oc * NHT + (size_t)b * NH + j3;
        minHR[idx] = m3R;
        minHG[idx] = m3G;
      }
    }
  }
}

// ======================= dispatch 2: mega2 (templated on split) ==============
template<int JS, int HCn>
__global__ __launch_bounds__(256) void mega2t(
    const float* __restrict__ recon, const float* __restrict__ gt,
    const float* __restrict__ rnorm, const float* __restrict__ gnorm,
    const float* __restrict__ obj,
    const float* __restrict__ mean, const float* __restrict__ logv,
    const float* __restrict__ vw,
    const float* __restrict__ keyR, const float* __restrict__ keyG,
    const float* __restrict__ priorK,
    const float* __restrict__ minHR, const float* __restrict__ minHG,
    float* __restrict__ accs, float* __restrict__ out)
{
  __shared__ float red[4][5];
  const int bid = blockIdx.x;
  const int tid = threadIdx.x;
  const int lane = tid & 63, wv = tid >> 6;

  if (bid < FIN_OBJ_BLKS) {
    // ---- obj finalize: slice loads + 2 gathers + epilogue ----
    const int b = bid / T2;
    const int tile = bid % T2;
    const int o = tile * 256 + tid;
    float penetr = 0.f, nptsv = 0.f, contactv = 0.f, consistv = 0.f, lossov = 0.f;
    if (o < NO) {
      const float* op = obj + ((size_t)b * NO + o) * 3;
      const float ox = op[0], oy = op[1], oz = op[2];
      const float o2 = ox*ox + oy*oy + oz*oz;
      const size_t base = (size_t)b * NO + o;

      float kR = 3.4e38f, kG = 3.4e38f, bP = 3.4e38f;
      #pragma unroll
      for (int s = 0; s < JS; ++s) {
        kR = fminf(kR, keyR[(size_t)s * NKEY + base]);
        kG = fminf(kG, keyG[(size_t)s * NKEY + base]);
        bP = fminf(bP, priorK[(size_t)s * NKEY + base]);
      }
      uint32 kRb = __float_as_uint(kR), kGb = __float_as_uint(kG);
      int idxR = (int)(kRb & 0x3FFu), idxG = (int)(kGb & 0x3FFu);
      float d2R = fmaxf(__uint_as_float(kRb & 0xFFFFFC00u) + o2, 0.f);
      float d2G = fmaxf(__uint_as_float(kGb & 0xFFFFFC00u) + o2, 0.f);
      float d2P = fmaxf(bP + o2, 0.f);

      const float* hR = recon + ((size_t)b * NH + idxR) * 3;
      const float* nR = rnorm + ((size_t)b * NH + idxR) * 3;
      float dotR = (ox - hR[0]) * nR[0] + (oy - hR[1]) * nR[1] + (oz - hR[2]) * nR[2];
      const float* hG = gt + ((size_t)b * NH + idxG) * 3;
      const float* nG = gnorm + ((size_t)b * NH + idxG) * 3;
      float dotG = (ox - hG[0]) * nG[0] + (oy - hG[1]) * nG[1] + (oz - hG[2]) * nG[2];

      float sgnR = (dotR > 0.f) ? 1.f : ((dotR < 0.f) ? -1.f : 0.f);
      float sgnG = (dotG > 0.f) ? 1.f : ((dotG < 0.f) ? -1.f : 0.f);
      float sR_ = sqrtf(d2R), sG_ = sqrtf(d2G);
      float o2h = sR_ * sgnR, o2hg = sG_ * sgnG;

      bool interior = dotR < 0.f;
      bool cmap = sG_ < 0.005f;
      bool rcmap = sR_ < 0.005f;

      penetr   = interior ? d2R : 0.f;
      nptsv    = cmap ? 1.f : 0.f;
      contactv = cmap ? d2P : 0.f;
      consistv = (cmap && rcmap) ? 1.f : 0.f;
      float w = (o2h < 0.f) ? 1.5f
              : (((o2hg < 0.01f) && (o2hg > -0.005f)) ? 1.f : 0.1f);
      lossov = fabsf(o2h - o2hg) * w;
    }

    float vals[5] = {penetr, nptsv, contactv, consistv, lossov};
    #pragma unroll
    for (int q = 0; q < 5; ++q) {
      float s = wave_sum(vals[q]);
      if (lane == 0) red[wv][q] = s;
    }
    __syncthreads();
    if (tid < 5) {
      float s = red[0][tid] + red[1][tid] + red[2][tid] + red[3][tid];
      atomicAdd(&accs[tid], s);
    }
  } else {
    // ---- tail: reduce hand-chunk mins, loss_h, recon_loss, KLD ----
    const int t = (bid - FIN_OBJ_BLKS) * 256 + tid;
    float lossh = 0.f, rsum = 0.f, ksum = 0.f;
    if (t < NB * NH) {
      const float* rp = recon + (size_t)t * 3;
      const float* gp = gt + (size_t)t * 3;
      float rx = rp[0], ry = rp[1], rz = rp[2];
      float gx = gp[0], gy = gp[1], gz = gp[2];
      float d0 = rx - gx, d1 = ry - gy, d2 = rz - gz;
      rsum = d0*d0 + d1*d1 + d2*d2;

      float mRt = 3.4e38f, mGt = 3.4e38f;
      #pragma unroll
      for (int c = 0; c < HCn; ++c) {
        mRt = fminf(mRt, minHR[(size_t)c * NHT + t]);
        mGt = fminf(mGt, minHG[(size_t)c * NHT + t]);
      }
      float r2 = rx*rx + ry*ry + rz*rz;
      float g2 = gx*gx + gy*gy + gz*gz;
      float d2Rh = fmaxf(mRt + r2, 0.f);
      float d2Gh = fmaxf(mGt + g2, 0.f);
      int j = t % NH;
      lossh = fabsf(sqrtf(d2Rh) - sqrtf(d2Gh)) * powf(vw[j], 0.4f);
    }
    if (t < NB * NZ) {
      float m = mean[t], lv = logv[t];
      ksum = 1.f + lv - m * m - expf(lv);
    }
    float vals[3] = {lossh, rsum, ksum};
    #pragma unroll
    for (int q = 0; q < 3; ++q) {
      float s = wave_sum(vals[q]);
      if (lane == 0) red[wv][q] = s;
    }
    __syncthreads();
    if (tid < 3) {
      float s = red[0][tid] + red[1][tid] + red[2][tid] + red[3][tid];
      atomicAdd(&accs[5 + tid], s);
    }
  }

  // ---- fused final: last block combines ----
  __syncthreads();
  if (tid == 0) {
    __threadfence();
    int* cnt = (int*)(accs + 8);
    int old = atomicAdd(cnt, 1);
    if (old == FIN_BLKS - 1) {
      float a[8];
      #pragma unroll
      for (int q = 0; q < 8; ++q) a[q] = atomicAdd(&accs[q], 0.0f);
      const float recon_loss = a[6] / (float)NB;
      const float kld = -0.5f * a[7] / (float)NB * 10.f;
      const float penetr = 100.f * a[0] / (float)NB;
      const float npts = a[1];
      const float contact = (npts > 0.f) ? (3000.f * a[2] / ((float)NB * npts)) : 0.f;
      const float consistency = -5.f * a[3] / (npts + 0.0001f);
      const float lossh = 35.f * (1.f - 0.005f) * (a[5] / (float)(NB * NH));
      const float losso = 30.f * (1.f - 0.005f) * (a[4] / (float)(NB * NO));
      out[0] = recon_loss + 0.1f * kld + 1000.f * penetr + 10.f * contact
             + 10.f * consistency + lossh + losso;
    }
  }
}

// =========================== PATH C (tiny ws fallback) ===========================
__global__ __launch_bounds__(256) void obj_mono(
    const float* __restrict__ recon, const float* __restrict__ gt,
    const float* __restrict__ rnorm, const float* __restrict__ gnorm,
    const float* __restrict__ obj, float* __restrict__ accs)
{
  __shared__ float4 sR[NH];
  __shared__ float4 sG[NH];
  __shared__ float red[4][5];
  const int b = blockIdx.x / 12;
  const int tile = blockIdx.x % 12;
  const int tid = threadIdx.x;
  for (int i = tid; i < NH; i += 256) {
    const float* p = recon + ((size_t)b * NH + i) * 3;
    float x = p[0], y = p[1], z = p[2];
    sR[i] = make_float4(x, y, z, x*x + y*y + z*z);
    const float* q = gt + ((size_t)b * NH + i) * 3;
    float gx = q[0], gy = q[1], gz = q[2];
    sG[i] = make_float4(gx, gy, gz, gx*gx + gy*gy + gz*gz);
  }
  __syncthreads();
  const int o = tile * 256 + tid;
  float penetr = 0.f, nptsv = 0.f, contactv = 0.f, consistv = 0.f, lossov = 0.f;
  if (o < NO) {
    const float* op = obj + ((size_t)b * NO + o) * 3;
    const float ox = op[0], oy = op[1], oz = op[2];
    const float nx = -2.f*ox, ny = -2.f*oy, nz = -2.f*oz;
    const float o2 = ox*ox + oy*oy + oz*oz;
    float bR = 3.4e38f, bG = 3.4e38f; int iR = 0, iG = 0;
    for (int i = 0; i < NH; ++i) {
      float4 h = sR[i];
      float t = fmaf(nx, h.x, h.w); t = fmaf(ny, h.y, t); t = fmaf(nz, h.z, t);
      if (t < bR) { bR = t; iR = i; }
      float4 g = sG[i];
      float u = fmaf(nx, g.x, g.w); u = fmaf(ny, g.y, u); u = fmaf(nz, g.z, u);
      if (u < bG) { bG = u; iG = i; }
    }
    float bP = 3.4e38f;
    for (int k = 0; k < NP; ++k) {
      float4 h = sR[c_prior[k]];
      float t = fmaf(nx, h.x, h.w); t = fmaf(ny, h.y, t); t = fmaf(nz, h.z, t);
      bP = fminf(bP, t);
    }
    float d2R = fmaxf(bR + o2, 0.f);
    float d2G = fmaxf(bG + o2, 0.f);
    float d2P = fmaxf(bP + o2, 0.f);
    float4 hR = sR[iR];
    const float* nR = rnorm + ((size_t)b * NH + iR) * 3;
    float dotR = (ox-hR.x)*nR[0] + (oy-hR.y)*nR[1] + (oz-hR.z)*nR[2];
    float4 hG = sG[iG];
    const float* nG = gnorm + ((size_t)b * NH + iG) * 3;
    float dotG = (ox-hG.x)*nG[0] + (oy-hG.y)*nG[1] + (oz-hG.z)*nG[2];
    float sgnR = (dotR > 0.f) ? 1.f : ((dotR < 0.f) ? -1.f : 0.f);
    float sgnG = (dotG > 0.f) ? 1.f : ((dotG < 0.f) ? -1.f : 0.f);
    float sR_ = sqrtf(d2R), sG_ = sqrtf(d2G);
    float o2h = sR_*sgnR, o2hg = sG_*sgnG;
    bool interior = dotR < 0.f;
    bool cmap = sG_ < 0.005f, rcmap = sR_ < 0.005f;
    penetr = interior ? d2R : 0.f;
    nptsv = cmap ? 1.f : 0.f;
    contactv = cmap ? d2P : 0.f;
    consistv = (cmap && rcmap) ? 1.f : 0.f;
    float w = (o2h < 0.f) ? 1.5f : (((o2hg < 0.01f) && (o2hg > -0.005f)) ? 1.f : 0.1f);
    lossov = fabsf(o2h - o2hg) * w;
  }
  float vals[5] = {penetr, nptsv, contactv, consistv, lossov};
  const int lane = tid & 63, wv = tid >> 6;
  for (int q = 0; q < 5; ++q) {
    float s = wave_sum(vals[q]);
    if (lane == 0) red[wv][q] = s;
  }
  __syncthreads();
  if (tid < 5) {
    float s = red[0][tid] + red[1][tid] + red[2][tid] + red[3][tid];
    atomicAdd(&accs[tid], s);
  }
}

__global__ __launch_bounds__(256) void hand_full(
    const float* __restrict__ recon, const float* __restrict__ gt,
    const float* __restrict__ obj, const float* __restrict__ vw,
    float* __restrict__ accs)
{
  __shared__ float4 sO[500];
  __shared__ float red[4];
  const int b = blockIdx.x >> 2;
  const int j = ((blockIdx.x & 3) << 8) + threadIdx.x;
  const bool valid = j < NH;
  float rx=0,ry=0,rz=0,gx=0,gy=0,gz=0;
  if (valid) {
    const float* rp = recon + ((size_t)b * NH + j) * 3;
    const float* gp = gt + ((size_t)b * NH + j) * 3;
    rx=rp[0];ry=rp[1];rz=rp[2]; gx=gp[0];gy=gp[1];gz=gp[2];
  }
  const float nrx=-2.f*rx, nry=-2.f*ry, nrz=-2.f*rz;
  const float ngx=-2.f*gx, ngy=-2.f*gy, ngz=-2.f*gz;
  const float r2 = rx*rx+ry*ry+rz*rz, g2 = gx*gx+gy*gy+gz*gz;
  float mR = 3.4e38f, mG = 3.4e38f;
  for (int oc = 0; oc < 6; ++oc) {
    __syncthreads();
    const float* Ob = obj + ((size_t)b * NO + oc * 500) * 3;
    for (int i = threadIdx.x; i < 500; i += 256) {
      float x = Ob[3*i], y = Ob[3*i+1], z = Ob[3*i+2];
      sO[i] = make_float4(x, y, z, x*x + y*y + z*z);
    }
    __syncthreads();
    if (valid) {
      for (int k = 0; k < 500; ++k) {
        float4 o4 = sO[k];
        float t = fmaf(nrx,o4.x,o4.w); t = fmaf(nry,o4.y,t); t = fmaf(nrz,o4.z,t);
        mR = fminf(mR, t);
        float u = fmaf(ngx,o4.x,o4.w); u = fmaf(ngy,o4.y,u); u = fmaf(ngz,o4.z,u);
        mG = fminf(mG, u);
      }
    }
  }
  float lossh = valid ? fabsf(sqrtf(fmaxf(mR+r2,0.f)) - sqrtf(fmaxf(mG+g2,0.f))) * powf(vw[j], 0.4f) : 0.f;
  const int lane = threadIdx.x & 63, wv = threadIdx.x >> 6;
  float s = wave_sum(lossh);
  if (lane == 0) red[wv] = s;
  __syncthreads();
  if (threadIdx.x == 0) atomicAdd(&accs[5], red[0]+red[1]+red[2]+red[3]);
}

__global__ __launch_bounds__(256) void tail_nomins(
    const float* __restrict__ recon, const float* __restrict__ gt,
    const float* __restrict__ mean, const float* __restrict__ logv,
    float* __restrict__ accs)
{
  __shared__ float red[4][2];
  const int t = blockIdx.x * 256 + threadIdx.x;
  float rsum = 0.f, ksum = 0.f;
  if (t < NB * NH) {
    const float* rp = recon + (size_t)t * 3;
    const float* gp = gt + (size_t)t * 3;
    float d0 = rp[0]-gp[0], d1 = rp[1]-gp[1], d2 = rp[2]-gp[2];
    rsum = d0*d0 + d1*d1 + d2*d2;
  }
  if (t < NB * NZ) {
    float m = mean[t], lv = logv[t];
    ksum = 1.f + lv - m*m - expf(lv);
  }
  float vals[2] = {rsum, ksum};
  const int lane = threadIdx.x & 63, wv = threadIdx.x >> 6;
  for (int q = 0; q < 2; ++q) {
    float s = wave_sum(vals[q]);
    if (lane == 0) red[wv][q] = s;
  }
  __syncthreads();
  if (threadIdx.x < 2) {
    float s = red[0][threadIdx.x] + red[1][threadIdx.x] + red[2][threadIdx.x] + red[3][threadIdx.x];
    atomicAdd(&accs[6 + threadIdx.x], s);
  }
}

__global__ void init_small(float* accs) {
  int t = threadIdx.x;
  if (t < 8) accs[t] = 0.0f;
}

__global__ void final_fb(const float* __restrict__ a, float* __restrict__ out) {
  const float recon_loss = a[6] / (float)NB;
  const float kld = -0.5f * a[7] / (float)NB * 10.f;
  const float penetr = 100.f * a[0] / (float)NB;
  const float npts = a[1];
  const float contact = (npts > 0.f) ? (3000.f * a[2] / ((float)NB * npts)) : 0.f;
  const float consistency = -5.f * a[3] / (npts + 0.0001f);
  const float lossh = 35.f * (1.f - 0.005f) * (a[5] / (float)NB / (float)NH);
  const float losso = 30.f * (1.f - 0.005f) * (a[4] / (float)(NB * NO));
  out[0] = recon_loss + 0.1f*kld + 1000.f*penetr + 10.f*contact + 10.f*consistency + lossh + losso;
}

extern "C" void kernel_launch(void* const* d_in, const int* in_sizes, int n_in,
                              void* d_out, int out_size, void* d_ws, size_t ws_size,
                              hipStream_t stream) {
  const float* recon = (const float*)d_in[0];
  const float* gt    = (const float*)d_in[1];
  const float* rnorm = (const float*)d_in[2];
  const float* gnorm = (const float*)d_in[3];
  const float* obj   = (const float*)d_in[4];
  const float* mean  = (const float*)d_in[5];
  const float* logv  = (const float*)d_in[6];
  const float* vw    = (const float*)d_in[7];
  float* out = (float*)d_out;

  // ws: accs[16] @0 | slices @256: keyR[JS*N] keyG[JS*N] priorK[JS*N]
  //                                minHR[HC*H] minHG[HC*H]
  float* accs = (float*)d_ws;
  float* base = (float*)((char*)d_ws + 256);

  // tier B (fine): JS=8, HC=24 -> 1536 mega1 blocks = 6 blocks/CU
  const size_t neededB = 256 + (3ull * 8 * NKEY + 2ull * 24 * NHT) * sizeof(float);
  // tier A (coarse): JS=4, HC=12 -> 768 mega1 blocks = 3 blocks/CU
  const size_t neededA = 256 + (3ull * 4 * NKEY + 2ull * 12 * NHT) * sizeof(float);

  if (ws_size >= neededB) {
    float* keyR   = base;
    float* keyG   = keyR + (size_t)8 * NKEY;
    float* priorK = keyG + (size_t)8 * NKEY;
    float* minHR  = priorK + (size_t)8 * NKEY;
    float* minHG  = minHR + (size_t)24 * NHT;
    const int g1 = NB * OBJ_TILES * 8 + NB * 24;   // 768 + 768 = 1536
    mega1t<8, 98, 24, 125><<<g1, 256, 0, stream>>>(
        recon, gt, obj, keyR, keyG, priorK, minHR, minHG, accs);
    mega2t<8, 24><<<FIN_BLKS, 256, 0, stream>>>(
        recon, gt, rnorm, gnorm, obj, mean, logv, vw,
        keyR, keyG, priorK, minHR, minHG, accs, out);
  } else if (ws_size >= neededA) {
    float* keyR   = base;
    float* keyG   = keyR + (size_t)4 * NKEY;
    float* priorK = keyG + (size_t)4 * NKEY;
    float* minHR  = priorK + (size_t)4 * NKEY;
    float* minHG  = minHR + (size_t)12 * NHT;
    const int g1 = NB * OBJ_TILES * 4 + NB * 12;   // 384 + 384 = 768
    mega1t<4, 195, 12, 250><<<g1, 256, 0, stream>>>(
        recon, gt, obj, keyR, keyG, priorK, minHR, minHG, accs);
    mega2t<4, 12><<<FIN_BLKS, 256, 0, stream>>>(
        recon, gt, rnorm, gnorm, obj, mean, logv, vw,
        keyR, keyG, priorK, minHR, minHG, accs, out);
  } else {
    init_small<<<1, 64, 0, stream>>>(accs);
    obj_mono<<<NB * 12, 256, 0, stream>>>(recon, gt, rnorm, gnorm, obj, accs);
    hand_full<<<NB * 4, 256, 0, stream>>>(recon, gt, obj, vw, accs);
    tail_nomins<<<(NB * NH + 255) / 256, 256, 0, stream>>>(recon, gt, mean, logv, accs);
    final_fb<<<1, 1, 0, stream>>>(accs, out);
  }
}

// Round 3
// 118.830 us; speedup vs baseline: 1.0415x; 1.0400x over previous
//
#include <hip/hip_runtime.h>
#include <math.h>

// GraspCVAE loss, MI355X — round 11.
// R10 post-mortem: no dispatch in the profile exceeds 42us, so mega1+mega2
// <= ~84us of the 123.6 total; mega2 is pinned just UNDER the top-5 cut
// (~41us) — it has been tied with mega1 all along. Its epilogue issues
// ~4300 device-scope atomicAdds that ALL land on one 64B cache line
// (accs[0..8]) -> serialized cross-XCD line ping-pong (matches R5/R7's
// measured 60-100us coherence cost).
// R11: pad each accumulator slot to its own 128B cache line (stride 32
// floats). Atomics to distinct lines drain in parallel (~480 ops/line,
// ~5-8us, overlapped). mega1 is byte-identical to R10 as the control.
// Predict: mega1 ~42 (unchanged), mega2 41 -> <=15, total -> ~95-105us.

#define NB 32
#define NH 778
#define NO 3000
#define NZ 64
#define NP 204

#define P_OBJ 4
#define OBJ_PTS 1024
#define OBJ_TILES 3                   // ceil(3000/1024)

#define T2 12                         // mega2 obj tiles (256 pts)
#define FIN_OBJ_BLKS (NB * T2)                // 384
#define FIN_TAIL_BLKS ((NB * NH + 255) / 256) // 98
#define FIN_BLKS (FIN_OBJ_BLKS + FIN_TAIL_BLKS) // 482

#define NKEY (NB * NO)                // 96000
#define NHT  (NB * NH)                // 24896

// accumulator padding: each logical slot q lives at accs[q*ACC_STRIDE]
#define ACC_STRIDE 32                 // 32 floats = 128 B = own cache line
#define ACC_SLOTS 16
#define ACC_FLOATS (ACC_SLOTS * ACC_STRIDE)   // 512 floats = 2048 B

typedef unsigned int uint32;

// original order (used by PATH C)
__device__ __constant__ int c_prior[NP] = {
  697,698,699,700,712,713,714,715,737,738,739,740,741,743,744,745,746,748,749,750,
  753,754,755,756,757,758,759,760,761,762,763,764,765,766,767,768,
  46,47,48,49,164,165,166,167,194,195,223,237,238,280,281,298,301,317,320,323,
  324,325,326,327,328,329,330,331,332,333,340,341,342,343,344,345,346,347,348,349,
  350,351,352,353,354,355,
  356,357,358,359,375,376,386,387,396,397,402,403,413,429,433,434,435,436,437,438,
  439,440,441,442,443,444,452,453,454,455,456,459,460,461,462,463,464,465,466,467,
  468,469,470,471,484,485,486,496,497,506,507,513,514,524,545,546,547,548,549,550,
  551,552,553,555,563,564,565,566,567,570,572,573,574,575,576,577,578,
  580,581,582,583,600,601,602,614,615,624,625,630,631,641,663,664,665,666,667,668,
  670,672,680,681,682,683,684,686,687,688,689,690,691,692,693,694,695,
  73,96,98,99,772,774,775,777
};

// globally ascending sorted prior list (usable for ANY contiguous j-split)
__device__ __constant__ int c_prior_sorted[NP] = {
  46,47,48,49,73,96,98,99,164,165,166,167,194,
  195,223,237,238,280,281,298,301,317,320,323,324,325,326,327,328,329,330,331,
  332,333,340,341,342,343,344,345,346,347,348,349,350,351,352,353,354,355,356,
  357,358,359,375,376,386,387,
  396,397,402,403,413,429,433,434,435,436,437,438,439,440,441,442,443,444,452,
  453,454,455,456,459,460,461,462,463,464,465,466,467,468,469,470,471,484,485,
  486,496,497,506,507,513,514,524,545,546,547,548,549,550,551,552,553,555,563,
  564,565,566,567,570,572,573,574,575,576,577,578,580,581,582,583,
  600,601,602,614,615,624,625,630,631,641,663,664,665,666,667,668,670,672,680,
  681,682,683,684,686,687,688,689,690,691,692,693,694,695,697,698,699,700,712,
  713,714,715,737,738,739,740,741,743,744,745,746,748,749,750,753,754,755,756,
  757,758,759,760,761,762,763,764,765,766,767,768,772,774,775,777
};
// split tables: position ranges in c_prior_sorted for j in [s*JC, (s+1)*JC)
__device__ __constant__ int c_psplit4[5] = {0, 13, 58, 131, 204};          // JC=195
__device__ __constant__ int c_psplit8[9] = {0, 6, 14, 19, 58, 97, 131, 154, 204}; // JC=98

__device__ inline float wave_sum(float v) {
  v += __shfl_down(v, 32);
  v += __shfl_down(v, 16);
  v += __shfl_down(v, 8);
  v += __shfl_down(v, 4);
  v += __shfl_down(v, 2);
  v += __shfl_down(v, 1);
  return v;
}

// forced 3-operand VALU ops (R9: verified correct, keeps instr count down)
__device__ __forceinline__ float f_min3(float a, float b, float c) {
  float r;
  asm("v_min3_f32 %0, %1, %2, %3" : "=v"(r) : "v"(a), "v"(b), "v"(c));
  return r;
}
__device__ __forceinline__ float f_packao(float t, int j, uint32 mask) {
  float r;
  asm("v_and_or_b32 %0, %1, %2, %3" : "=v"(r) : "v"(t), "s"(mask), "v"(j));
  return r;
}

// ======================= dispatch 1: mega1 (templated on split) ==============
// accs logical slots (each at q*ACC_STRIDE): 0 penetr, 1 npts, 2 contact,
// 3 consist, 4 loss_o, 5 loss_h, 6 recon_sq, 7 kld, 8 counter(int)
template<int JS, int JC, int HCn, int HCSn>
__global__ __launch_bounds__(256) void mega1t(
    const float* __restrict__ recon, const float* __restrict__ gt,
    const float* __restrict__ obj,
    float* __restrict__ keyR, float* __restrict__ keyG,
    float* __restrict__ priorK,
    float* __restrict__ minHR, float* __restrict__ minHG,
    float* __restrict__ accs)
{
  const int OBJ_B = NB * OBJ_TILES * JS;
  const int bid = blockIdx.x;
  const int tid = threadIdx.x;
  const uint32 KMASK = 0xFFFFFC00u;

  if (bid == 0) {  // zero padded accumulator region (consumed after boundary)
    accs[tid] = 0.0f;
    accs[tid + 256] = 0.0f;
  }

  if (bid < OBJ_B) {
    // ---- obj -> hand NN (j-split JS) + in-pass partial prior-NN ----
    __shared__ float4 shA[JC];   // recon split
    __shared__ float4 shB[JC];   // gt split
    const int b     = bid / (OBJ_TILES * JS);
    const int rem   = bid % (OBJ_TILES * JS);
    const int tile  = rem / JS;
    const int split = rem % JS;
    const int jbase = split * JC;
    const int jcnt  = (NH - jbase < JC) ? (NH - jbase) : JC;

    for (int i = tid; i < jcnt; i += 256) {
      const float* p = recon + ((size_t)b * NH + jbase + i) * 3;
      float x = p[0], y = p[1], z = p[2];
      shA[i] = make_float4(x, y, z, x*x + y*y + z*z);
      const float* q = gt + ((size_t)b * NH + jbase + i) * 3;
      float gx = q[0], gy = q[1], gz = q[2];
      shB[i] = make_float4(gx, gy, gz, gx*gx + gy*gy + gz*gz);
    }
    __syncthreads();

    float nx[P_OBJ], ny[P_OBJ], nz[P_OBJ];
    int ob[P_OBJ]; bool val[P_OBJ];
    #pragma unroll
    for (int m = 0; m < P_OBJ; ++m) {
      int o = tile * OBJ_PTS + m * 256 + tid;
      ob[m] = o; val[m] = (o < NO);
      float x = 0.f, y = 0.f, z = 0.f;
      if (val[m]) {
        const float* op = obj + ((size_t)b * NO + o) * 3;
        x = op[0]; y = op[1]; z = op[2];
      }
      nx[m] = -2.f * x; ny[m] = -2.f * y; nz[m] = -2.f * z;
    }

    float bR[P_OBJ], bG[P_OBJ];
    #pragma unroll
    for (int m = 0; m < P_OBJ; ++m) { bR[m] = 3.4e38f; bG[m] = 3.4e38f; }

#define RSTEP(hh0, hh1, jj0, jj1) \
    { _Pragma("unroll") for (int m = 0; m < P_OBJ; ++m) { \
        float t0 = fmaf(nx[m], hh0.x, hh0.w); t0 = fmaf(ny[m], hh0.y, t0); t0 = fmaf(nz[m], hh0.z, t0); \
        float t1 = fmaf(nx[m], hh1.x, hh1.w); t1 = fmaf(ny[m], hh1.y, t1); t1 = fmaf(nz[m], hh1.z, t1); \
        bR[m] = f_min3(bR[m], f_packao(t0, jj0, KMASK), f_packao(t1, jj1, KMASK)); } }
#define GSTEP(gg0, gg1, jj0, jj1) \
    { _Pragma("unroll") for (int m = 0; m < P_OBJ; ++m) { \
        float u0 = fmaf(nx[m], gg0.x, gg0.w); u0 = fmaf(ny[m], gg0.y, u0); u0 = fmaf(nz[m], gg0.z, u0); \
        float u1 = fmaf(nx[m], gg1.x, gg1.w); u1 = fmaf(ny[m], gg1.y, u1); u1 = fmaf(nz[m], gg1.z, u1); \
        bG[m] = f_min3(bG[m], f_packao(u0, jj0, KMASK), f_packao(u1, jj1, KMASK)); } }

    // interleaved prefetch: every LDS read pair is covered by a 36-VALU phase
    float4 h0 = shA[0], h1 = shA[1];
    int i = 0;
    for (; i + 3 < jcnt; i += 2) {
      float4 g0 = shB[i], g1 = shB[i + 1];     // issue G loads
      RSTEP(h0, h1, jbase + i, jbase + i + 1); // compute R (covers G latency)
      float4 hn0 = shA[i + 2], hn1 = shA[i + 3]; // issue next A loads
      GSTEP(g0, g1, jbase + i, jbase + i + 1); // compute G (covers A latency)
      h0 = hn0; h1 = hn1;
    }
    { // last preloaded pair (i, i+1 valid by loop parity)
      float4 g0 = shB[i], g1 = shB[i + 1];
      RSTEP(h0, h1, jbase + i, jbase + i + 1);
      GSTEP(g0, g1, jbase + i, jbase + i + 1);
      i += 2;
    }
    for (; i < jcnt; ++i) {      // 0-1 leftover singles
      float4 hh = shA[i], gg = shB[i];
      #pragma unroll
      for (int m = 0; m < P_OBJ; ++m) {
        float t0 = fmaf(nx[m], hh.x, hh.w); t0 = fmaf(ny[m], hh.y, t0); t0 = fmaf(nz[m], hh.z, t0);
        bR[m] = fminf(bR[m], f_packao(t0, jbase + i, KMASK));
        float u0 = fmaf(nx[m], gg.x, gg.w); u0 = fmaf(ny[m], gg.y, u0); u0 = fmaf(nz[m], gg.z, u0);
        bG[m] = fminf(bG[m], f_packao(u0, jbase + i, KMASK));
      }
    }
#undef RSTEP
#undef GSTEP

    // partial prior-NN over this split's prior members (candidates in shA)
    float bP[P_OBJ];
    #pragma unroll
    for (int m = 0; m < P_OBJ; ++m) bP[m] = 3.4e38f;
    const int* psp = (JS == 8) ? c_psplit8 : c_psplit4;
    const int pk0 = psp[split], pk1 = psp[split + 1];
    int k = pk0;
    for (; k + 1 < pk1; k += 2) {
      float4 ha = shA[c_prior_sorted[k] - jbase];
      float4 hb = shA[c_prior_sorted[k + 1] - jbase];
      #pragma unroll
      for (int m = 0; m < P_OBJ; ++m) {
        float t = fmaf(nx[m], ha.x, ha.w); t = fmaf(ny[m], ha.y, t); t = fmaf(nz[m], ha.z, t);
        float u = fmaf(nx[m], hb.x, hb.w); u = fmaf(ny[m], hb.y, u); u = fmaf(nz[m], hb.z, u);
        bP[m] = f_min3(bP[m], t, u);
      }
    }
    if (k < pk1) {
      float4 ha = shA[c_prior_sorted[k] - jbase];
      #pragma unroll
      for (int m = 0; m < P_OBJ; ++m) {
        float t = fmaf(nx[m], ha.x, ha.w); t = fmaf(ny[m], ha.y, t); t = fmaf(nz[m], ha.z, t);
        bP[m] = fminf(bP[m], t);
      }
    }

    #pragma unroll
    for (int m = 0; m < P_OBJ; ++m) {
      if (!val[m]) continue;
      const size_t idx = (size_t)split * NKEY + (size_t)b * NO + ob[m];
      keyR[idx] = bR[m];
      keyG[idx] = bG[m];
      priorK[idx] = bP[m];
    }
  } else {
    // ---- hand -> obj NN, HCn chunks; prefetched k-loop + rotating tail ----
    __shared__ float4 sO[HCSn];
    const int bid2 = bid - OBJ_B;
    const int oc = bid2 % HCn;
    const int b  = bid2 / HCn;

    const float* Ob = obj + ((size_t)b * NO + oc * HCSn) * 3;
    for (int i2 = tid; i2 < HCSn; i2 += 256) {
      float x = Ob[3*i2], y = Ob[3*i2+1], z = Ob[3*i2+2];
      sO[i2] = make_float4(x, y, z, x*x + y*y + z*z);
    }
    __syncthreads();

    float nrx[3], nry[3], nrz[3];
    float ngx[3], ngy[3], ngz[3];
    #pragma unroll
    for (int m = 0; m < 3; ++m) {
      const int j = m * 256 + tid;                 // 0..767, always valid
      const float* rp = recon + ((size_t)b * NH + j) * 3;
      const float* gp = gt    + ((size_t)b * NH + j) * 3;
      nrx[m] = -2.f*rp[0]; nry[m] = -2.f*rp[1]; nrz[m] = -2.f*rp[2];
      ngx[m] = -2.f*gp[0]; ngy[m] = -2.f*gp[1]; ngz[m] = -2.f*gp[2];
    }

    float mR[3], mG[3];
    #pragma unroll
    for (int m = 0; m < 3; ++m) { mR[m] = 3.4e38f; mG[m] = 3.4e38f; }

#define HSTEP(oo0, oo1) \
    { _Pragma("unroll") for (int m = 0; m < 3; ++m) { \
        float t0 = fmaf(nrx[m], oo0.x, oo0.w); t0 = fmaf(nry[m], oo0.y, t0); t0 = fmaf(nrz[m], oo0.z, t0); \
        float t1 = fmaf(nrx[m], oo1.x, oo1.w); t1 = fmaf(nry[m], oo1.y, t1); t1 = fmaf(nrz[m], oo1.z, t1); \
        mR[m] = f_min3(mR[m], t0, t1); \
        float u0 = fmaf(ngx[m], oo0.x, oo0.w); u0 = fmaf(ngy[m], oo0.y, u0); u0 = fmaf(ngz[m], oo0.z, u0); \
        float u1 = fmaf(ngx[m], oo1.x, oo1.w); u1 = fmaf(ngy[m], oo1.y, u1); u1 = fmaf(ngz[m], oo1.z, u1); \
        mG[m] = f_min3(mG[m], u0, u1); } }

    float4 o0 = sO[0], o1 = sO[1];
    int k2 = 0;
    for (; k2 + 3 < HCSn; k2 += 2) {
      float4 a0 = sO[k2 + 2], a1 = sO[k2 + 3];   // prefetch next pair
      HSTEP(o0, o1);
      o0 = a0; o1 = a1;
    }
    HSTEP(o0, o1);                                // last preloaded pair
    k2 += 2;
    for (; k2 < HCSn; ++k2) {                     // 0-1 leftover singles
      float4 oc4 = sO[k2];
      #pragma unroll
      for (int m = 0; m < 3; ++m) {
        float t0 = fmaf(nrx[m], oc4.x, oc4.w); t0 = fmaf(nry[m], oc4.y, t0); t0 = fmaf(nrz[m], oc4.z, t0);
        mR[m] = fminf(mR[m], t0);
        float u0 = fmaf(ngx[m], oc4.x, oc4.w); u0 = fmaf(ngy[m], oc4.y, u0); u0 = fmaf(ngz[m], oc4.z, u0);
        mG[m] = fminf(mG[m], u0);
      }
    }
#undef HSTEP

    #pragma unroll
    for (int m = 0; m < 3; ++m) {
      const int j = m * 256 + tid;
      const size_t idx = (size_t)oc * NHT + (size_t)b * NH + j;
      minHR[idx] = mR[m];
      minHG[idx] = mG[m];
    }

    // tail: hand points 768..777 on one wave, rotated per block
    const int tw = bid2 & 3;
    if ((tid >> 6) == tw) {
      const int j3 = 768 + (tid & 63);
      const bool v3 = (j3 < NH);                   // lanes 0..9
      float rx=0.f,ry=0.f,rz=0.f,gx=0.f,gy=0.f,gz=0.f;
      if (v3) {
        const float* rp = recon + ((size_t)b * NH + j3) * 3;
        const float* gp = gt    + ((size_t)b * NH + j3) * 3;
        rx=rp[0];ry=rp[1];rz=rp[2]; gx=gp[0];gy=gp[1];gz=gp[2];
      }
      const float n3rx=-2.f*rx, n3ry=-2.f*ry, n3rz=-2.f*rz;
      const float n3gx=-2.f*gx, n3gy=-2.f*gy, n3gz=-2.f*gz;
      float m3R = 3.4e38f, m3G = 3.4e38f;
      int k3 = 0;
      for (; k3 + 1 < HCSn; k3 += 2) {
        float4 q0 = sO[k3], q1 = sO[k3 + 1];
        float t0 = fmaf(n3rx, q0.x, q0.w); t0 = fmaf(n3ry, q0.y, t0); t0 = fmaf(n3rz, q0.z, t0);
        float t1 = fmaf(n3rx, q1.x, q1.w); t1 = fmaf(n3ry, q1.y, t1); t1 = fmaf(n3rz, q1.z, t1);
        m3R = f_min3(m3R, t0, t1);
        float u0 = fmaf(n3gx, q0.x, q0.w); u0 = fmaf(n3gy, q0.y, u0); u0 = fmaf(n3gz, q0.z, u0);
        float u1 = fmaf(n3gx, q1.x, q1.w); u1 = fmaf(n3gy, q1.y, u1); u1 = fmaf(n3gz, q1.z, u1);
        m3G = f_min3(m3G, u0, u1);
      }
      if (HCSn & 1) {
        float4 q0 = sO[HCSn - 1];
        float t0 = fmaf(n3rx, q0.x, q0.w); t0 = fmaf(n3ry, q0.y, t0); t0 = fmaf(n3rz, q0.z, t0);
        m3R = fminf(m3R, t0);
        float u0 = fmaf(n3gx, q0.x, q0.w); u0 = fmaf(n3gy, q0.y, u0); u0 = fmaf(n3gz, q0.z, u0);
        m3G = fminf(m3G, u0);
      }
      if (v3) {
        const size_t idx = (size_t)oc * NHT + (size_t)b * NH + j3;
        minHR[idx] = m3R;
        minHG[idx] = m3G;
      }
    }
  }
}

// ======================= dispatch 2: mega2 (templated on split) ==============
template<int JS, int HCn>
__global__ __launch_bounds__(256) void mega2t(
    const float* __restrict__ recon, const float* __restrict__ gt,
    const float* __restrict__ rnorm, const float* __restrict__ gnorm,
    const float* __restrict__ obj,
    const float* __restrict__ mean, const float* __restrict__ logv,
    const float* __restrict__ vw,
    const float* __restrict__ keyR, const float* __restrict__ keyG,
    const float* __restrict__ priorK,
    const float* __restrict__ minHR, const float* __restrict__ minHG,
    float* __restrict__ accs, float* __restrict__ out)
{
  __shared__ float red[4][5];
  const int bid = blockIdx.x;
  const int tid = threadIdx.x;
  const int lane = tid & 63, wv = tid >> 6;

  if (bid < FIN_OBJ_BLKS) {
    // ---- obj finalize: slice loads + 2 gathers + epilogue ----
    const int b = bid / T2;
    const int tile = bid % T2;
    const int o = tile * 256 + tid;
    float penetr = 0.f, nptsv = 0.f, contactv = 0.f, consistv = 0.f, lossov = 0.f;
    if (o < NO) {
      const float* op = obj + ((size_t)b * NO + o) * 3;
      const float ox = op[0], oy = op[1], oz = op[2];
      const float o2 = ox*ox + oy*oy + oz*oz;
      const size_t base = (size_t)b * NO + o;

      float kR = 3.4e38f, kG = 3.4e38f, bP = 3.4e38f;
      #pragma unroll
      for (int s = 0; s < JS; ++s) {
        kR = fminf(kR, keyR[(size_t)s * NKEY + base]);
        kG = fminf(kG, keyG[(size_t)s * NKEY + base]);
        bP = fminf(bP, priorK[(size_t)s * NKEY + base]);
      }
      uint32 kRb = __float_as_uint(kR), kGb = __float_as_uint(kG);
      int idxR = (int)(kRb & 0x3FFu), idxG = (int)(kGb & 0x3FFu);
      float d2R = fmaxf(__uint_as_float(kRb & 0xFFFFFC00u) + o2, 0.f);
      float d2G = fmaxf(__uint_as_float(kGb & 0xFFFFFC00u) + o2, 0.f);
      float d2P = fmaxf(bP + o2, 0.f);

      const float* hR = recon + ((size_t)b * NH + idxR) * 3;
      const float* nR = rnorm + ((size_t)b * NH + idxR) * 3;
      float dotR = (ox - hR[0]) * nR[0] + (oy - hR[1]) * nR[1] + (oz - hR[2]) * nR[2];
      const float* hG = gt + ((size_t)b * NH + idxG) * 3;
      const float* nG = gnorm + ((size_t)b * NH + idxG) * 3;
      float dotG = (ox - hG[0]) * nG[0] + (oy - hG[1]) * nG[1] + (oz - hG[2]) * nG[2];

      float sgnR = (dotR > 0.f) ? 1.f : ((dotR < 0.f) ? -1.f : 0.f);
      float sgnG = (dotG > 0.f) ? 1.f : ((dotG < 0.f) ? -1.f : 0.f);
      float sR_ = sqrtf(d2R), sG_ = sqrtf(d2G);
      float o2h = sR_ * sgnR, o2hg = sG_ * sgnG;

      bool interior = dotR < 0.f;
      bool cmap = sG_ < 0.005f;
      bool rcmap = sR_ < 0.005f;

      penetr   = interior ? d2R : 0.f;
      nptsv    = cmap ? 1.f : 0.f;
      contactv = cmap ? d2P : 0.f;
      consistv = (cmap && rcmap) ? 1.f : 0.f;
      float w = (o2h < 0.f) ? 1.5f
              : (((o2hg < 0.01f) && (o2hg > -0.005f)) ? 1.f : 0.1f);
      lossov = fabsf(o2h - o2hg) * w;
    }

    float vals[5] = {penetr, nptsv, contactv, consistv, lossov};
    #pragma unroll
    for (int q = 0; q < 5; ++q) {
      float s = wave_sum(vals[q]);
      if (lane == 0) red[wv][q] = s;
    }
    __syncthreads();
    if (tid < 5) {
      float s = red[0][tid] + red[1][tid] + red[2][tid] + red[3][tid];
      atomicAdd(&accs[tid * ACC_STRIDE], s);
    }
  } else {
    // ---- tail: reduce hand-chunk mins, loss_h, recon_loss, KLD ----
    const int t = (bid - FIN_OBJ_BLKS) * 256 + tid;
    float lossh = 0.f, rsum = 0.f, ksum = 0.f;
    if (t < NB * NH) {
      const float* rp = recon + (size_t)t * 3;
      const float* gp = gt + (size_t)t * 3;
      float rx = rp[0], ry = rp[1], rz = rp[2];
      float gx = gp[0], gy = gp[1], gz = gp[2];
      float d0 = rx - gx, d1 = ry - gy, d2 = rz - gz;
      rsum = d0*d0 + d1*d1 + d2*d2;

      float mRt = 3.4e38f, mGt = 3.4e38f;
      #pragma unroll
      for (int c = 0; c < HCn; ++c) {
        mRt = fminf(mRt, minHR[(size_t)c * NHT + t]);
        mGt = fminf(mGt, minHG[(size_t)c * NHT + t]);
      }
      float r2 = rx*rx + ry*ry + rz*rz;
      float g2 = gx*gx + gy*gy + gz*gz;
      float d2Rh = fmaxf(mRt + r2, 0.f);
      float d2Gh = fmaxf(mGt + g2, 0.f);
      int j = t % NH;
      lossh = fabsf(sqrtf(d2Rh) - sqrtf(d2Gh)) * powf(vw[j], 0.4f);
    }
    if (t < NB * NZ) {
      float m = mean[t], lv = logv[t];
      ksum = 1.f + lv - m * m - expf(lv);
    }
    float vals[3] = {lossh, rsum, ksum};
    #pragma unroll
    for (int q = 0; q < 3; ++q) {
      float s = wave_sum(vals[q]);
      if (lane == 0) red[wv][q] = s;
    }
    __syncthreads();
    if (tid < 3) {
      float s = red[0][tid] + red[1][tid] + red[2][tid] + red[3][tid];
      atomicAdd(&accs[(5 + tid) * ACC_STRIDE], s);
    }
  }

  // ---- fused final: last block combines ----
  __syncthreads();
  if (tid == 0) {
    __threadfence();
    int* cnt = (int*)(accs + 8 * ACC_STRIDE);
    int old = atomicAdd(cnt, 1);
    if (old == FIN_BLKS - 1) {
      float a[8];
      #pragma unroll
      for (int q = 0; q < 8; ++q) a[q] = atomicAdd(&accs[q * ACC_STRIDE], 0.0f);
      const float recon_loss = a[6] / (float)NB;
      const float kld = -0.5f * a[7] / (float)NB * 10.f;
      const float penetr = 100.f * a[0] / (float)NB;
      const float npts = a[1];
      const float contact = (npts > 0.f) ? (3000.f * a[2] / ((float)NB * npts)) : 0.f;
      const float consistency = -5.f * a[3] / (npts + 0.0001f);
      const float lossh = 35.f * (1.f - 0.005f) * (a[5] / (float)(NB * NH));
      const float losso = 30.f * (1.f - 0.005f) * (a[4] / (float)(NB * NO));
      out[0] = recon_loss + 0.1f * kld + 1000.f * penetr + 10.f * contact
             + 10.f * consistency + lossh + losso;
    }
  }
}

// =========================== PATH C (tiny ws fallback) ===========================
__global__ __launch_bounds__(256) void obj_mono(
    const float* __restrict__ recon, const float* __restrict__ gt,
    const float* __restrict__ rnorm, const float* __restrict__ gnorm,
    const float* __restrict__ obj, float* __restrict__ accs)
{
  __shared__ float4 sR[NH];
  __shared__ float4 sG[NH];
  __shared__ float red[4][5];
  const int b = blockIdx.x / 12;
  const int tile = blockIdx.x % 12;
  const int tid = threadIdx.x;
  for (int i = tid; i < NH; i += 256) {
    const float* p = recon + ((size_t)b * NH + i) * 3;
    float x = p[0], y = p[1], z = p[2];
    sR[i] = make_float4(x, y, z, x*x + y*y + z*z);
    const float* q = gt + ((size_t)b * NH + i) * 3;
    float gx = q[0], gy = q[1], gz = q[2];
    sG[i] = make_float4(gx, gy, gz, gx*gx + gy*gy + gz*gz);
  }
  __syncthreads();
  const int o = tile * 256 + tid;
  float penetr = 0.f, nptsv = 0.f, contactv = 0.f, consistv = 0.f, lossov = 0.f;
  if (o < NO) {
    const float* op = obj + ((size_t)b * NO + o) * 3;
    const float ox = op[0], oy = op[1], oz = op[2];
    const float nx = -2.f*ox, ny = -2.f*oy, nz = -2.f*oz;
    const float o2 = ox*ox + oy*oy + oz*oz;
    float bR = 3.4e38f, bG = 3.4e38f; int iR = 0, iG = 0;
    for (int i = 0; i < NH; ++i) {
      float4 h = sR[i];
      float t = fmaf(nx, h.x, h.w); t = fmaf(ny, h.y, t); t = fmaf(nz, h.z, t);
      if (t < bR) { bR = t; iR = i; }
      float4 g = sG[i];
      float u = fmaf(nx, g.x, g.w); u = fmaf(ny, g.y, u); u = fmaf(nz, g.z, u);
      if (u < bG) { bG = u; iG = i; }
    }
    float bP = 3.4e38f;
    for (int k = 0; k < NP; ++k) {
      float4 h = sR[c_prior[k]];
      float t = fmaf(nx, h.x, h.w); t = fmaf(ny, h.y, t); t = fmaf(nz, h.z, t);
      bP = fminf(bP, t);
    }
    float d2R = fmaxf(bR + o2, 0.f);
    float d2G = fmaxf(bG + o2, 0.f);
    float d2P = fmaxf(bP + o2, 0.f);
    float4 hR = sR[iR];
    const float* nR = rnorm + ((size_t)b * NH + iR) * 3;
    float dotR = (ox-hR.x)*nR[0] + (oy-hR.y)*nR[1] + (oz-hR.z)*nR[2];
    float4 hG = sG[iG];
    const float* nG = gnorm + ((size_t)b * NH + iG) * 3;
    float dotG = (ox-hG.x)*nG[0] + (oy-hG.y)*nG[1] + (oz-hG.z)*nG[2];
    float sgnR = (dotR > 0.f) ? 1.f : ((dotR < 0.f) ? -1.f : 0.f);
    float sgnG = (dotG > 0.f) ? 1.f : ((dotG < 0.f) ? -1.f : 0.f);
    float sR_ = sqrtf(d2R), sG_ = sqrtf(d2G);
    float o2h = sR_*sgnR, o2hg = sG_*sgnG;
    bool interior = dotR < 0.f;
    bool cmap = sG_ < 0.005f, rcmap = sR_ < 0.005f;
    penetr = interior ? d2R : 0.f;
    nptsv = cmap ? 1.f : 0.f;
    contactv = cmap ? d2P : 0.f;
    consistv = (cmap && rcmap) ? 1.f : 0.f;
    float w = (o2h < 0.f) ? 1.5f : (((o2hg < 0.01f) && (o2hg > -0.005f)) ? 1.f : 0.1f);
    lossov = fabsf(o2h - o2hg) * w;
  }
  float vals[5] = {penetr, nptsv, contactv, consistv, lossov};
  const int lane = tid & 63, wv = tid >> 6;
  for (int q = 0; q < 5; ++q) {
    float s = wave_sum(vals[q]);
    if (lane == 0) red[wv][q] = s;
  }
  __syncthreads();
  if (tid < 5) {
    float s = red[0][tid] + red[1][tid] + red[2][tid] + red[3][tid];
    atomicAdd(&accs[tid * ACC_STRIDE], s);
  }
}

__global__ __launch_bounds__(256) void hand_full(
    const float* __restrict__ recon, const float* __restrict__ gt,
    const float* __restrict__ obj, const float* __restrict__ vw,
    float* __restrict__ accs)
{
  __shared__ float4 sO[500];
  __shared__ float red[4];
  const int b = blockIdx.x >> 2;
  const int j = ((blockIdx.x & 3) << 8) + threadIdx.x;
  const bool valid = j < NH;
  float rx=0,ry=0,rz=0,gx=0,gy=0,gz=0;
  if (valid) {
    const float* rp = recon + ((size_t)b * NH + j) * 3;
    const float* gp = gt + ((size_t)b * NH + j) * 3;
    rx=rp[0];ry=rp[1];rz=rp[2]; gx=gp[0];gy=gp[1];gz=gp[2];
  }
  const float nrx=-2.f*rx, nry=-2.f*ry, nrz=-2.f*rz;
  const float ngx=-2.f*gx, ngy=-2.f*gy, ngz=-2.f*gz;
  const float r2 = rx*rx+ry*ry+rz*rz, g2 = gx*gx+gy*gy+gz*gz;
  float mR = 3.4e38f, mG = 3.4e38f;
  for (int oc = 0; oc < 6; ++oc) {
    __syncthreads();
    const float* Ob = obj + ((size_t)b * NO + oc * 500) * 3;
    for (int i = threadIdx.x; i < 500; i += 256) {
      float x = Ob[3*i], y = Ob[3*i+1], z = Ob[3*i+2];
      sO[i] = make_float4(x, y, z, x*x + y*y + z*z);
    }
    __syncthreads();
    if (valid) {
      for (int k = 0; k < 500; ++k) {
        float4 o4 = sO[k];
        float t = fmaf(nrx,o4.x,o4.w); t = fmaf(nry,o4.y,t); t = fmaf(nrz,o4.z,t);
        mR = fminf(mR, t);
        float u = fmaf(ngx,o4.x,o4.w); u = fmaf(ngy,o4.y,u); u = fmaf(ngz,o4.z,u);
        mG = fminf(mG, u);
      }
    }
  }
  float lossh = valid ? fabsf(sqrtf(fmaxf(mR+r2,0.f)) - sqrtf(fmaxf(mG+g2,0.f))) * powf(vw[j], 0.4f) : 0.f;
  const int lane = threadIdx.x & 63, wv = threadIdx.x >> 6;
  float s = wave_sum(lossh);
  if (lane == 0) red[wv] = s;
  __syncthreads();
  if (threadIdx.x == 0) atomicAdd(&accs[5 * ACC_STRIDE], red[0]+red[1]+red[2]+red[3]);
}

__global__ __launch_bounds__(256) void tail_nomins(
    const float* __restrict__ recon, const float* __restrict__ gt,
    const float* __restrict__ mean, const float* __restrict__ logv,
    float* __restrict__ accs)
{
  __shared__ float red[4][2];
  const int t = blockIdx.x * 256 + threadIdx.x;
  float rsum = 0.f, ksum = 0.f;
  if (t < NB * NH) {
    const float* rp = recon + (size_t)t * 3;
    const float* gp = gt + (size_t)t * 3;
    float d0 = rp[0]-gp[0], d1 = rp[1]-gp[1], d2 = rp[2]-gp[2];
    rsum = d0*d0 + d1*d1 + d2*d2;
  }
  if (t < NB * NZ) {
    float m = mean[t], lv = logv[t];
    ksum = 1.f + lv - m*m - expf(lv);
  }
  float vals[2] = {rsum, ksum};
  const int lane = threadIdx.x & 63, wv = threadIdx.x >> 6;
  for (int q = 0; q < 2; ++q) {
    float s = wave_sum(vals[q]);
    if (lane == 0) red[wv][q] = s;
  }
  __syncthreads();
  if (threadIdx.x < 2) {
    float s = red[0][threadIdx.x] + red[1][threadIdx.x] + red[2][threadIdx.x] + red[3][threadIdx.x];
    atomicAdd(&accs[(6 + threadIdx.x) * ACC_STRIDE], s);
  }
}

__global__ void init_small(float* accs) {
  int t = threadIdx.x;
  accs[t] = 0.0f;
  accs[t + 256] = 0.0f;
}

__global__ void final_fb(const float* __restrict__ a, float* __restrict__ out) {
  const float recon_loss = a[6 * ACC_STRIDE] / (float)NB;
  const float kld = -0.5f * a[7 * ACC_STRIDE] / (float)NB * 10.f;
  const float penetr = 100.f * a[0] / (float)NB;
  const float npts = a[1 * ACC_STRIDE];
  const float contact = (npts > 0.f) ? (3000.f * a[2 * ACC_STRIDE] / ((float)NB * npts)) : 0.f;
  const float consistency = -5.f * a[3 * ACC_STRIDE] / (npts + 0.0001f);
  const float lossh = 35.f * (1.f - 0.005f) * (a[5 * ACC_STRIDE] / (float)(NB * NH));
  const float losso = 30.f * (1.f - 0.005f) * (a[4 * ACC_STRIDE] / (float)(NB * NO));
  out[0] = recon_loss + 0.1f*kld + 1000.f*penetr + 10.f*contact + 10.f*consistency + lossh + losso;
}

extern "C" void kernel_launch(void* const* d_in, const int* in_sizes, int n_in,
                              void* d_out, int out_size, void* d_ws, size_t ws_size,
                              hipStream_t stream) {
  const float* recon = (const float*)d_in[0];
  const float* gt    = (const float*)d_in[1];
  const float* rnorm = (const float*)d_in[2];
  const float* gnorm = (const float*)d_in[3];
  const float* obj   = (const float*)d_in[4];
  const float* mean  = (const float*)d_in[5];
  const float* logv  = (const float*)d_in[6];
  const float* vw    = (const float*)d_in[7];
  float* out = (float*)d_out;

  // ws: padded accs[512] @0 (2048B) | slices @2048: keyR[JS*N] keyG[JS*N]
  //     priorK[JS*N] minHR[HC*H] minHG[HC*H]
  float* accs = (float*)d_ws;
  float* base = (float*)((char*)d_ws + ACC_FLOATS * sizeof(float));

  // tier B (fine): JS=8, HC=24 -> 1536 mega1 blocks = 6 blocks/CU
  const size_t neededB = ACC_FLOATS * sizeof(float)
                       + (3ull * 8 * NKEY + 2ull * 24 * NHT) * sizeof(float);
  // tier A (coarse): JS=4, HC=12 -> 768 mega1 blocks = 3 blocks/CU
  const size_t neededA = ACC_FLOATS * sizeof(float)
                       + (3ull * 4 * NKEY + 2ull * 12 * NHT) * sizeof(float);

  if (ws_size >= neededB) {
    float* keyR   = base;
    float* keyG   = keyR + (size_t)8 * NKEY;
    float* priorK = keyG + (size_t)8 * NKEY;
    float* minHR  = priorK + (size_t)8 * NKEY;
    float* minHG  = minHR + (size_t)24 * NHT;
    const int g1 = NB * OBJ_TILES * 8 + NB * 24;   // 768 + 768 = 1536
    mega1t<8, 98, 24, 125><<<g1, 256, 0, stream>>>(
        recon, gt, obj, keyR, keyG, priorK, minHR, minHG, accs);
    mega2t<8, 24><<<FIN_BLKS, 256, 0, stream>>>(
        recon, gt, rnorm, gnorm, obj, mean, logv, vw,
        keyR, keyG, priorK, minHR, minHG, accs, out);
  } else if (ws_size >= neededA) {
    float* keyR   = base;
    float* keyG   = keyR + (size_t)4 * NKEY;
    float* priorK = keyG + (size_t)4 * NKEY;
    float* minHR  = priorK + (size_t)4 * NKEY;
    float* minHG  = minHR + (size_t)12 * NHT;
    const int g1 = NB * OBJ_TILES * 4 + NB * 12;   // 384 + 384 = 768
    mega1t<4, 195, 12, 250><<<g1, 256, 0, stream>>>(
        recon, gt, obj, keyR, keyG, priorK, minHR, minHG, accs);
    mega2t<4, 12><<<FIN_BLKS, 256, 0, stream>>>(
        recon, gt, rnorm, gnorm, obj, mean, logv, vw,
        keyR, keyG, priorK, minHR, minHG, accs, out);
  } else {
    init_small<<<1, 256, 0, stream>>>(accs);
    obj_mono<<<NB * 12, 256, 0, stream>>>(recon, gt, rnorm, gnorm, obj, accs);
    hand_full<<<NB * 4, 256, 0, stream>>>(recon, gt, obj, vw, accs);
    tail_nomins<<<(NB * NH + 255) / 256, 256, 0, stream>>>(recon, gt, mean, logv, accs);
    final_fb<<<1, 1, 0, stream>>>(accs, out);
  }
}